// Round 1
// 1263.492 us; speedup vs baseline: 1.0235x; 1.0235x over previous
//
#include <hip/hip_runtime.h>
#include <math.h>

// ---- problem constants ----
#define BATCH  32
#define NTOK   577
#define CDIM   1024
#define C3DIM  3072
#define H4DIM  4096
#define NHEAD  16
#define MROWS  (BATCH * NTOK)   // 18464
#define NPADV  584              // 577 rounded up to 8 (V^T row pad)

typedef __bf16 bf16x8 __attribute__((ext_vector_type(8)));
typedef float  f32x4  __attribute__((ext_vector_type(4)));
typedef unsigned short u16x8 __attribute__((ext_vector_type(8)));

__device__ __forceinline__ float bf2f(unsigned short u) {
    union { unsigned int i; float f; } v; v.i = ((unsigned int)u) << 16; return v.f;
}
__device__ __forceinline__ unsigned short f2bf(float f) {
    union { float f; unsigned int i; } v; v.f = f;
    unsigned int r = v.i + 0x7FFFu + ((v.i >> 16) & 1u);
    return (unsigned short)(r >> 16);
}
__device__ __forceinline__ bf16x8 ld_bf8(const unsigned short* p) {
    return __builtin_bit_cast(bf16x8, *(const u16x8*)p);
}

// async global->LDS, 16B per lane. LDS dest = wave-uniform base + lane*16.
typedef const __attribute__((address_space(1))) unsigned int* gptr_t;
typedef __attribute__((address_space(3))) unsigned int* lptr_t;
__device__ __forceinline__ void gl2lds(const void* g, const void* l) {
    __builtin_amdgcn_global_load_lds(
        (gptr_t)(unsigned long long)g,
        (lptr_t)(unsigned int)(unsigned long long)l,
        16, 0, 0);
}

// Q pre-scale: Dh^-0.5 * log2(e), so softmax runs in exp2 domain
#define QSCALE 0.18033688011112042f

// ---------------- f32 -> bf16 convert ----------------
__global__ __launch_bounds__(256) void conv_kernel(const float* __restrict__ src,
                                                   unsigned short* __restrict__ dst, int n) {
    int i = (blockIdx.x * 256 + threadIdx.x) * 4;
    if (i < n) {
        float4 v = *(const float4*)(src + i);
        dst[i]     = f2bf(v.x);
        dst[i + 1] = f2bf(v.y);
        dst[i + 2] = f2bf(v.z);
        dst[i + 3] = f2bf(v.w);
    }
}

// ---------------- LayerNorm ----------------
template<bool F32IN>
__global__ __launch_bounds__(256) void ln_kernel(
    const void* __restrict__ X,
    const float* __restrict__ w,
    const float* __restrict__ b,
    unsigned short* __restrict__ out)
{
    const int row = blockIdx.x;
    const int t = threadIdx.x;
    float vals[4]; float s = 0.f, ss = 0.f;
#pragma unroll
    for (int i = 0; i < 4; i++) {
        int c = t + i * 256;
        float v;
        if (F32IN) v = ((const float*)X)[(size_t)row * CDIM + c];
        else       v = bf2f(((const unsigned short*)X)[(size_t)row * CDIM + c]);
        vals[i] = v; s += v; ss += v * v;
    }
#pragma unroll
    for (int off = 32; off > 0; off >>= 1) { s += __shfl_xor(s, off); ss += __shfl_xor(ss, off); }
    __shared__ float red[8];
    if ((t & 63) == 0) { red[t >> 6] = s; red[4 + (t >> 6)] = ss; }
    __syncthreads();
    s  = red[0] + red[1] + red[2] + red[3];
    ss = red[4] + red[5] + red[6] + red[7];
    float mu  = s * (1.f / CDIM);
    float var = ss * (1.f / CDIM) - mu * mu;
    float rs  = rsqrtf(var + 1e-6f);
#pragma unroll
    for (int i = 0; i < 4; i++) {
        int c = t + i * 256;
        float o = (vals[i] - mu) * rs * w[c] + b[c];
        out[(size_t)row * CDIM + c] = f2bf(o);
    }
}

// ---------------- GEMM 256x256, BK=64, 8 waves, 2-phase prefetch pipeline ----
// Out = A[M,K]bf16 @ W[N,K]bf16^T + epilogue
// OP=0: +bias, qkv split-scatter (Out=Qb *QSCALE, Out2=Kb, Out3=Vt transposed)
// OP=1: +bias, + f32 residual (Res=x), bf16 out (x1)
// OP=2: +bias, GELU (tanh-form, exp2+rcp), bf16 out (fc1)
// OP=3: +bias, + bf16 residual (x1), f32 out to d_out
// OP=4: f32 accumulate into d_out (no bias)
//
// Pipeline (learn_hip "minimum 2-phase", m230/m248-verified recipe):
//   prologue: STAGE(buf0, t=0); __syncthreads();
//   loop t:   STAGE(buf[cur^1], t+1)   // loads in flight across the whole body
//             ds_read buf[cur] + 64 MFMA
//             __syncthreads()          // vmcnt(0)+lgkmcnt(0)+barrier: next tile ready
// One barrier per K-step (old kernel had two, with zero load/compute overlap).
template<int OP>
__global__ __launch_bounds__(512, 2) void gemm256(
    const unsigned short* __restrict__ A,
    const unsigned short* __restrict__ W, int Wstride,
    const unsigned short* __restrict__ bias,
    const void* __restrict__ Res,
    void* __restrict__ Out,
    void* __restrict__ Out2,
    void* __restrict__ Out3,
    int K, int Nout)
{
    // 2 buffers x (256 rows x 64 cols) for A and B: 128 KiB total
    __shared__ __align__(16) unsigned short Alds[2][256 * 64];
    __shared__ __align__(16) unsigned short Blds[2][256 * 64];

    const int tid  = threadIdx.x;
    const int lane = tid & 63, wave = tid >> 6;
    const int q = lane >> 4, l16 = lane & 15;
    const int wm = (wave >> 2) << 7;   // 0 or 128 (M half)
    const int wn = (wave & 3) << 6;    // 0/64/128/192 (N quarter)
    const int tileM = blockIdx.y << 8, tileN = blockIdx.x << 8;

    f32x4 acc[8][4];
#pragma unroll
    for (int i = 0; i < 8; i++)
#pragma unroll
        for (int j = 0; j < 4; j++) acc[i][j] = (f32x4){0.f, 0.f, 0.f, 0.f};

    // staging: issue j covers rows [j*64, j*64+64); thread -> (row = j*64 + tid/8, 8-elem chunk tid%8)
    const int srow = tid >> 3;          // 0..63
    const int scol = (tid & 7) << 3;    // 0..56
    const unsigned short* pA[4];
    const unsigned short* pB[4];
#pragma unroll
    for (int j = 0; j < 4; j++) {
        int ra = tileM + j * 64 + srow; if (ra > MROWS - 1) ra = MROWS - 1;
        pA[j] = A + (size_t)ra * K + scol;
        pB[j] = W + (size_t)(tileN + j * 64 + srow) * Wstride + scol;
    }

    // wave-uniform LDS element base for issue j: j*4096 + wave*512 (HW adds lane*16B)
    auto STAGE = [&](int buf, int k0) {
#pragma unroll
        for (int j = 0; j < 4; j++) {
            gl2lds(pA[j] + k0, &Alds[buf][j * 4096 + wave * 512]);
            gl2lds(pB[j] + k0, &Blds[buf][j * 4096 + wave * 512]);
        }
    };

    auto COMPUTE = [&](int buf) {
#pragma unroll
        for (int ks = 0; ks < 2; ks++) {
            bf16x8 af[8], bfr[4];
#pragma unroll
            for (int mi = 0; mi < 8; mi++)
                af[mi] = ld_bf8(&Alds[buf][(wm + mi * 16 + l16) * 64 + ks * 32 + q * 8]);
#pragma unroll
            for (int ni = 0; ni < 4; ni++)
                bfr[ni] = ld_bf8(&Blds[buf][(wn + ni * 16 + l16) * 64 + ks * 32 + q * 8]);
#pragma unroll
            for (int mi = 0; mi < 8; mi++)
#pragma unroll
                for (int ni = 0; ni < 4; ni++)
                    acc[mi][ni] = __builtin_amdgcn_mfma_f32_16x16x32_bf16(af[mi], bfr[ni], acc[mi][ni], 0, 0, 0);
        }
    };

    const int NT = K >> 6;
    STAGE(0, 0);
    __syncthreads();           // drains vmcnt(0): buf0 populated
    int cur = 0;
    for (int t = 0; t < NT; ++t) {
        if (t + 1 < NT) STAGE(cur ^ 1, (t + 1) << 6);
        COMPUTE(cur);
        __syncthreads();       // vmcnt(0): prefetch landed; barrier: all reads of cur done
        cur ^= 1;
    }

    // ---- epilogue: 128 outputs/thread ----
#pragma unroll
    for (int mi = 0; mi < 8; mi++) {
#pragma unroll
        for (int r = 0; r < 4; r++) {
            int row = tileM + wm + mi * 16 + q * 4 + r;
            if (row >= MROWS) continue;
            unsigned int bb = 0, nn = 0;
            if constexpr (OP == 0) {
                bb = ((unsigned int)row * 58154u) >> 25;   // row/577, exact for row<78766
                nn = (unsigned int)row - bb * 577u;
            }
#pragma unroll
            for (int ni = 0; ni < 4; ni++) {
                int col = tileN + wn + ni * 16 + l16;
                size_t oidx = (size_t)row * Nout + col;
                float v = acc[mi][ni][r];
                if constexpr (OP != 4) v += bf2f(bias[col]);
                if constexpr (OP == 0) {
                    int s = col >> 10, h = (col >> 6) & 15, d = col & 63;
                    size_t bh = (size_t)(bb * 16 + h);
                    if (s == 0)      ((unsigned short*)Out )[(bh * NTOK + nn) * 64 + d] = f2bf(v * QSCALE);
                    else if (s == 1) ((unsigned short*)Out2)[(bh * NTOK + nn) * 64 + d] = f2bf(v);
                    else             ((unsigned short*)Out3)[(bh * 64 + d) * NPADV + nn] = f2bf(v);
                } else if constexpr (OP == 1) {
                    v += ((const float*)Res)[oidx];
                    ((unsigned short*)Out)[oidx] = f2bf(v);
                } else if constexpr (OP == 2) {
                    // GELU tanh-form: x*sigmoid(2y), y = 0.79788456(x + 0.044715x^3),
                    // in exp2 domain; max |err| vs erf-GELU ~3e-4 << bf16 noise.
                    float z = exp2f(v * fmaf(v * v, 0.1029432f, 2.3022082f));
                    v = v - v * __builtin_amdgcn_rcpf(1.0f + z);
                    ((unsigned short*)Out)[oidx] = f2bf(v);
                } else if constexpr (OP == 3) {
                    v += bf2f(((const unsigned short*)Res)[oidx]);
                    ((float*)Out)[oidx] = v;
                } else {
                    ((float*)Out)[oidx] += v;
                }
            }
        }
    }
}

// ---------------- Flash attention, no-max unnormalized softmax ----------------
// Scores are O(1): bf16/LN-bounded inputs make f32 exp overflow (s>88) unreachable,
// so skip the running max / alpha rescale entirely; divide by l once at the end.
// Qb pre-scaled by QSCALE (exp2 domain). Grid: 1D 5120, XCD-swizzled so the 10
// q-tiles of one (b,h) share an XCD (flat%8 == same) for K/V L2 reuse.
__global__ __launch_bounds__(256) void attn_kernel(
    const unsigned short* __restrict__ Qb,
    const unsigned short* __restrict__ Kb,
    const unsigned short* __restrict__ Vt,
    unsigned short* __restrict__ o)
{
    const int flat = blockIdx.x;
    const int x8 = flat & 7;
    const int g = flat >> 3;
    const int qt = g % 10;
    const int bh = (g / 10) * 8 + x8;      // b*16 + h
    const int q0 = qt * 64;
    const int tid = threadIdx.x;
    const int wv = tid >> 6, lane = tid & 63;
    const int qd = lane >> 4, l16 = lane & 15;

    __shared__ __align__(16) unsigned short Ps[4][16 * 72];

    const unsigned short* Qh = Qb + (size_t)bh * NTOK * 64;
    const unsigned short* Kh = Kb + (size_t)bh * NTOK * 64;
    const unsigned short* Vh = Vt + (size_t)bh * 64 * NPADV;

    int qrow = q0 + wv * 16 + l16;
    int qr = qrow < NTOK ? qrow : NTOK - 1;
    bf16x8 qf0 = ld_bf8(Qh + (size_t)qr * 64 + qd * 8);
    bf16x8 qf1 = ld_bf8(Qh + (size_t)qr * 64 + 32 + qd * 8);

    float lsum[4];
    f32x4 Oacc[4];
#pragma unroll
    for (int r = 0; r < 4; r++) lsum[r] = 0.f;
#pragma unroll
    for (int ni = 0; ni < 4; ni++) Oacc[ni] = (f32x4){0.f, 0.f, 0.f, 0.f};

    for (int kt = 0; kt < 10; kt++) {
        const int k0 = kt * 64;
        const bool tail = (kt == 9);
        f32x4 sacc[4];
#pragma unroll
        for (int ni = 0; ni < 4; ni++) sacc[ni] = (f32x4){0.f, 0.f, 0.f, 0.f};
#pragma unroll
        for (int ni = 0; ni < 4; ni++) {
            int krow = k0 + ni * 16 + l16;
            if (krow > NTOK - 1) krow = NTOK - 1;
            const unsigned short* kp = Kh + (size_t)krow * 64 + qd * 8;
            bf16x8 b0 = ld_bf8(kp);
            bf16x8 b1 = ld_bf8(kp + 32);
            sacc[ni] = __builtin_amdgcn_mfma_f32_16x16x32_bf16(qf0, b0, sacc[ni], 0, 0, 0);
            sacc[ni] = __builtin_amdgcn_mfma_f32_16x16x32_bf16(qf1, b1, sacc[ni], 0, 0, 0);
        }

        // P = exp2(S) (Q pre-scaled into log2 domain); accumulate row-sum partials
#pragma unroll
        for (int r = 0; r < 4; r++) {
#pragma unroll
            for (int ni = 0; ni < 4; ni++) {
                float pv = exp2f(sacc[ni][r]);
                if (tail && (k0 + ni * 16 + l16 >= NTOK)) pv = 0.f;
                lsum[r] += pv;
                Ps[wv][(qd * 4 + r) * 72 + ni * 16 + l16] = f2bf(pv);
            }
        }
        // per-wave private LDS region: intra-wave DS ordering, no barrier needed

        // O += P @ V   (contract over keys; V^T rows = head dims)
#pragma unroll
        for (int kk = 0; kk < 2; kk++) {
            bf16x8 a = ld_bf8(&Ps[wv][l16 * 72 + kk * 32 + qd * 8]);
            int kchunk = k0 + kk * 32 + qd * 8;
            if (kchunk > NTOK - 1) kchunk = NTOK - 1;  // clamped chunks have P==0
#pragma unroll
            for (int ni = 0; ni < 4; ni++) {
                bf16x8 bb = ld_bf8(Vh + (size_t)(ni * 16 + l16) * NPADV + kchunk);
                Oacc[ni] = __builtin_amdgcn_mfma_f32_16x16x32_bf16(a, bb, Oacc[ni], 0, 0, 0);
            }
        }
    }

    // one cross-lane reduce at the end (sum over 16 key-columns)
#pragma unroll
    for (int r = 0; r < 4; r++)
#pragma unroll
        for (int off = 8; off > 0; off >>= 1) lsum[r] += __shfl_xor(lsum[r], off);

    const int b = bh >> 4, h = bh & 15;
#pragma unroll
    for (int r = 0; r < 4; r++) {
        int gq = q0 + wv * 16 + qd * 4 + r;
        if (gq >= NTOK) continue;
        float inv = 1.0f / lsum[r];
#pragma unroll
        for (int ni = 0; ni < 4; ni++) {
            int d = ni * 16 + l16;
            o[((size_t)b * NTOK + gq) * CDIM + (size_t)h * 64 + d] = f2bf(Oacc[ni][r] * inv);
        }
    }
}

// ---------------- launch ----------------
extern "C" void kernel_launch(void* const* d_in, const int* in_sizes, int n_in,
                              void* d_out, int out_size, void* d_ws, size_t ws_size,
                              hipStream_t stream) {
    (void)in_sizes; (void)n_in; (void)out_size;
    const float* x      = (const float*)d_in[0];
    const float* ln1_w  = (const float*)d_in[1];
    const float* ln1_b  = (const float*)d_in[2];
    const float* qkv_w  = (const float*)d_in[3];
    const float* qkv_b  = (const float*)d_in[4];
    const float* proj_w = (const float*)d_in[5];
    const float* proj_b = (const float*)d_in[6];
    const float* ln2_w  = (const float*)d_in[7];
    const float* ln2_b  = (const float*)d_in[8];
    const float* fc1_w  = (const float*)d_in[9];
    const float* fc1_b  = (const float*)d_in[10];
    const float* fc2_w  = (const float*)d_in[11];
    const float* fc2_b  = (const float*)d_in[12];

    // ---- ws layout: converted weights, then big regions ----
    char* ws = (char*)d_ws;
    size_t off = 0;
    auto alloc = [&](size_t els) { void* p = ws + off; off += els * 2; return (unsigned short*)p; };
    unsigned short* qkvw_b  = alloc(3145728);
    unsigned short* projw_b = alloc(1048576);
    unsigned short* fc1w_b  = alloc(4194304);
    unsigned short* fc2w_b  = alloc(4194304);
    unsigned short* qkvb_b  = alloc(3072);
    unsigned short* projb_b = alloc(1024);
    unsigned short* fc1b_b  = alloc(4096);
    unsigned short* fc2b_b  = alloc(1024);
    off = (off + 255) & ~(size_t)255;
    unsigned short* R1 = (unsigned short*)(ws + off); off += (size_t)MROWS * 1024 * 2;          // Kb -> x1
    unsigned short* R2 = (unsigned short*)(ws + off); off += (size_t)512 * 64 * NPADV * 2;      // Vt -> h2
    unsigned short* R3 = (unsigned short*)(ws + off);                                           // fc1 out
    size_t rem = ws_size > off ? ws_size - off : 0;
    const int CH = rem >= (size_t)MROWS * H4DIM * 2 ? H4DIM
                 : (rem >= (size_t)MROWS * 1024 * 2 ? 1024
                 : (rem >= (size_t)MROWS * 512 * 2 ? 512 : 256));

    // d_out (f32 [M,1024] = 75.6MB) used as scratch: half1 = Qb, half2 = h1 then obuf
    unsigned short* Qb   = (unsigned short*)d_out;
    unsigned short* h1   = Qb + (size_t)MROWS * 1024;
    unsigned short* obuf = h1;
    unsigned short* Kb = R1;
    unsigned short* Vt = R2;
    unsigned short* x1 = R1;
    unsigned short* h2 = R2;

    // weight/bias conversion (every call; graph-safe)
    conv_kernel<<<3145728 / 1024, 256, 0, stream>>>(qkv_w,  qkvw_b,  3145728);
    conv_kernel<<<1048576 / 1024, 256, 0, stream>>>(proj_w, projw_b, 1048576);
    conv_kernel<<<4194304 / 1024, 256, 0, stream>>>(fc1_w,  fc1w_b,  4194304);
    conv_kernel<<<4194304 / 1024, 256, 0, stream>>>(fc2_w,  fc2w_b,  4194304);
    conv_kernel<<<3, 256, 0, stream>>>(qkv_b,  qkvb_b,  3072);
    conv_kernel<<<1, 256, 0, stream>>>(proj_b, projb_b, 1024);
    conv_kernel<<<4, 256, 0, stream>>>(fc1_b,  fc1b_b,  4096);
    conv_kernel<<<1, 256, 0, stream>>>(fc2_b,  fc2b_b,  1024);

    const int mt = (MROWS + 255) / 256;  // 73

    // h1 = LN1(x)
    ln_kernel<true><<<MROWS, 256, 0, stream>>>(x, ln1_w, ln1_b, h1);
    // qkv GEMM -> split Qb/Kb/Vt
    gemm256<0><<<dim3(C3DIM / 256, mt), 512, 0, stream>>>(
        h1, qkvw_b, CDIM, qkvb_b, nullptr, Qb, Kb, Vt, CDIM, C3DIM);
    // attention -> obuf (overwrites h1; h1 dead)
    attn_kernel<<<5120, 256, 0, stream>>>(Qb, Kb, Vt, obuf);
    // x1 = bf16(x + obuf @ proj_w^T + proj_b)    (Kb dead)
    gemm256<1><<<dim3(CDIM / 256, mt), 512, 0, stream>>>(
        obuf, projw_b, CDIM, projb_b, x, x1, nullptr, nullptr, CDIM, CDIM);
    // h2 = LN2(x1)   (Vt dead)
    ln_kernel<false><<<MROWS, 256, 0, stream>>>(x1, ln2_w, ln2_b, h2);

    if (CH == H4DIM) {
        // full MLP: one fc1, one fc2 (d_out free: Qb/obuf dead)
        gemm256<2><<<dim3(H4DIM / 256, mt), 512, 0, stream>>>(
            h2, fc1w_b, CDIM, fc1b_b, nullptr, R3, nullptr, nullptr, CDIM, H4DIM);
        gemm256<3><<<dim3(CDIM / 256, mt), 512, 0, stream>>>(
            R3, fc2w_b, H4DIM, fc2b_b, x1, d_out, nullptr, nullptr, H4DIM, CDIM);
    } else {
        for (int c0 = 0; c0 < H4DIM; c0 += CH) {
            gemm256<2><<<dim3(CH / 256, mt), 512, 0, stream>>>(
                h2, fc1w_b + (size_t)c0 * CDIM, CDIM, fc1b_b + c0, nullptr, R3, nullptr, nullptr, CDIM, CH);
            if (c0 == 0)
                gemm256<3><<<dim3(CDIM / 256, mt), 512, 0, stream>>>(
                    R3, fc2w_b, H4DIM, fc2b_b, x1, d_out, nullptr, nullptr, CH, CDIM);
            else
                gemm256<4><<<dim3(CDIM / 256, mt), 512, 0, stream>>>(
                    R3, fc2w_b + c0, H4DIM, nullptr, nullptr, d_out, nullptr, nullptr, CH, CDIM);
        }
    }
}

// Round 2
// 1229.557 us; speedup vs baseline: 1.0518x; 1.0276x over previous
//
#include <hip/hip_runtime.h>
#include <math.h>

// ---- problem constants ----
#define BATCH  32
#define NTOK   577
#define CDIM   1024
#define C3DIM  3072
#define H4DIM  4096
#define NHEAD  16
#define MROWS  (BATCH * NTOK)   // 18464
#define NPADV  584              // 577 rounded up to 8 (V^T row pad)

typedef __bf16 bf16x8 __attribute__((ext_vector_type(8)));
typedef float  f32x4  __attribute__((ext_vector_type(4)));
typedef unsigned short u16x8 __attribute__((ext_vector_type(8)));

__device__ __forceinline__ float bf2f(unsigned short u) {
    union { unsigned int i; float f; } v; v.i = ((unsigned int)u) << 16; return v.f;
}
__device__ __forceinline__ unsigned short f2bf(float f) {
    union { float f; unsigned int i; } v; v.f = f;
    unsigned int r = v.i + 0x7FFFu + ((v.i >> 16) & 1u);
    return (unsigned short)(r >> 16);
}
__device__ __forceinline__ bf16x8 ld_bf8(const unsigned short* p) {
    return __builtin_bit_cast(bf16x8, *(const u16x8*)p);
}

// async global->LDS, 16B per lane. LDS dest = wave-uniform base + lane*16.
typedef const __attribute__((address_space(1))) unsigned int* gptr_t;
typedef __attribute__((address_space(3))) unsigned int* lptr_t;
__device__ __forceinline__ void gl2lds(const void* g, const void* l) {
    __builtin_amdgcn_global_load_lds(
        (gptr_t)(unsigned long long)g,
        (lptr_t)(unsigned int)(unsigned long long)l,
        16, 0, 0);
}

// Q pre-scale: Dh^-0.5 * log2(e), so softmax runs in exp2 domain
#define QSCALE 0.18033688011112042f

// GELU tanh-form in exp2 domain: max |err| vs erf-GELU ~3e-4 << bf16 noise.
__device__ __forceinline__ float gelu_f(float v) {
    float z = exp2f(v * fmaf(v * v, 0.1029432f, 2.3022082f));
    return v - v * __builtin_amdgcn_rcpf(1.0f + z);
}

// ---------------- f32 -> bf16 convert ----------------
__global__ __launch_bounds__(256) void conv_kernel(const float* __restrict__ src,
                                                   unsigned short* __restrict__ dst, int n) {
    int i = (blockIdx.x * 256 + threadIdx.x) * 4;
    if (i < n) {
        float4 v = *(const float4*)(src + i);
        dst[i]     = f2bf(v.x);
        dst[i + 1] = f2bf(v.y);
        dst[i + 2] = f2bf(v.z);
        dst[i + 3] = f2bf(v.w);
    }
}

// ---------------- LayerNorm ----------------
template<bool F32IN>
__global__ __launch_bounds__(256) void ln_kernel(
    const void* __restrict__ X,
    const float* __restrict__ w,
    const float* __restrict__ b,
    unsigned short* __restrict__ out)
{
    const int row = blockIdx.x;
    const int t = threadIdx.x;
    float vals[4]; float s = 0.f, ss = 0.f;
#pragma unroll
    for (int i = 0; i < 4; i++) {
        int c = t + i * 256;
        float v;
        if (F32IN) v = ((const float*)X)[(size_t)row * CDIM + c];
        else       v = bf2f(((const unsigned short*)X)[(size_t)row * CDIM + c]);
        vals[i] = v; s += v; ss += v * v;
    }
#pragma unroll
    for (int off = 32; off > 0; off >>= 1) { s += __shfl_xor(s, off); ss += __shfl_xor(ss, off); }
    __shared__ float red[8];
    if ((t & 63) == 0) { red[t >> 6] = s; red[4 + (t >> 6)] = ss; }
    __syncthreads();
    s  = red[0] + red[1] + red[2] + red[3];
    ss = red[4] + red[5] + red[6] + red[7];
    float mu  = s * (1.f / CDIM);
    float var = ss * (1.f / CDIM) - mu * mu;
    float rs  = rsqrtf(var + 1e-6f);
#pragma unroll
    for (int i = 0; i < 4; i++) {
        int c = t + i * 256;
        float o = (vals[i] - mu) * rs * w[c] + b[c];
        out[(size_t)row * CDIM + c] = f2bf(o);
    }
}

// ============ GEMM A: 128x128 tile, BK=32, 4 waves, 16 KiB LDS ============
// High-occupancy variant (~7-10 waves/CU): best for small-N GEMMs (N=1024 ->
// 1160 blocks, ~95% packing) where the 256-tile grid (292 blocks) wave-quantizes
// to 57%. Busy-CU rate ~874-912 TF at K=4096 (m97 structure).
// OP=1: +bias, + f32 residual (Res=x), bf16 out (x1)
// OP=3: +bias, + bf16 residual (x1), f32 out to d_out
// OP=4: f32 accumulate into d_out (no bias)
template<int OP>
__global__ __launch_bounds__(256) void gemm128(
    const unsigned short* __restrict__ A,
    const unsigned short* __restrict__ W, int Wstride,
    const unsigned short* __restrict__ bias,
    const void* __restrict__ Res,
    void* __restrict__ Out,
    int K, int Nout)
{
    __shared__ __align__(16) unsigned short Alds[128 * 32];
    __shared__ __align__(16) unsigned short Blds[128 * 32];
    const int tid  = threadIdx.x;
    const int lane = tid & 63, wave = tid >> 6;
    const int q = lane >> 4, l16 = lane & 15;
    const int wm = (wave & 1) << 6, wn = (wave >> 1) << 6;
    const int tileM = blockIdx.y << 7, tileN = blockIdx.x << 7;

    f32x4 acc[4][4];
#pragma unroll
    for (int i = 0; i < 4; i++)
#pragma unroll
        for (int j = 0; j < 4; j++) acc[i][j] = (f32x4){0.f, 0.f, 0.f, 0.f};

    const int srow = tid >> 2;
    const int soff = (tid & 3) << 3;
    int arow1 = tileM + srow;       if (arow1 > MROWS - 1) arow1 = MROWS - 1;
    int arow2 = tileM + srow + 64;  if (arow2 > MROWS - 1) arow2 = MROWS - 1;
    const unsigned short* Aptr  = A + (size_t)arow1 * K + soff;
    const unsigned short* Aptr2 = A + (size_t)arow2 * K + soff;
    const unsigned short* Wp    = W + (size_t)(tileN + srow) * Wstride + soff;
    const unsigned short* Wp2   = Wp + (size_t)64 * Wstride;

    for (int k0 = 0; k0 < K; k0 += 32) {
        __syncthreads();   // all reads of previous tile complete
        gl2lds(Aptr  + k0, &Alds[wave * 512]);
        gl2lds(Aptr2 + k0, &Alds[2048 + wave * 512]);
        gl2lds(Wp    + k0, &Blds[wave * 512]);
        gl2lds(Wp2   + k0, &Blds[2048 + wave * 512]);
        __syncthreads();   // drains vmcnt -> LDS populated
        bf16x8 af[4], bfr[4];
#pragma unroll
        for (int mi = 0; mi < 4; mi++) af[mi]  = ld_bf8(&Alds[(wm + mi * 16 + l16) * 32 + q * 8]);
#pragma unroll
        for (int ni = 0; ni < 4; ni++) bfr[ni] = ld_bf8(&Blds[(wn + ni * 16 + l16) * 32 + q * 8]);
#pragma unroll
        for (int mi = 0; mi < 4; mi++)
#pragma unroll
            for (int ni = 0; ni < 4; ni++)
                acc[mi][ni] = __builtin_amdgcn_mfma_f32_16x16x32_bf16(af[mi], bfr[ni], acc[mi][ni], 0, 0, 0);
    }

#pragma unroll
    for (int mi = 0; mi < 4; mi++) {
#pragma unroll
        for (int r = 0; r < 4; r++) {
            int row = tileM + wm + mi * 16 + q * 4 + r;
            if (row >= MROWS) continue;
#pragma unroll
            for (int ni = 0; ni < 4; ni++) {
                int col = tileN + wn + ni * 16 + l16;
                size_t oidx = (size_t)row * Nout + col;
                float v = acc[mi][ni][r];
                if constexpr (OP != 4) v += bf2f(bias[col]);
                if constexpr (OP == 1) {
                    v += ((const float*)Res)[oidx];
                    ((unsigned short*)Out)[oidx] = f2bf(v);
                } else if constexpr (OP == 3) {
                    v += bf2f(((const unsigned short*)Res)[oidx]);
                    ((float*)Out)[oidx] = v;
                } else {
                    ((float*)Out)[oidx] += v;
                }
            }
        }
    }
}

// ============ GEMM B: 256x256 tile, BK=64, 8 waves, 2-phase prefetch ========
// 1 block/CU (128 KiB LDS); busy-CU rate ~900 TF. Use only when the grid has
// enough blocks to pack 256 CUs (N>=3072 here: qkv 876 blocks, fc1 1168).
// OP=0: +bias, qkv split-scatter (Out=Qb *QSCALE, Out2=Kb, Out3=Vt transposed)
// OP=2: +bias, GELU, bf16 out (fc1)
template<int OP>
__global__ __launch_bounds__(512, 2) void gemm256(
    const unsigned short* __restrict__ A,
    const unsigned short* __restrict__ W, int Wstride,
    const unsigned short* __restrict__ bias,
    void* __restrict__ Out,
    void* __restrict__ Out2,
    void* __restrict__ Out3,
    int K, int Nout)
{
    __shared__ __align__(16) unsigned short Alds[2][256 * 64];
    __shared__ __align__(16) unsigned short Blds[2][256 * 64];

    const int tid  = threadIdx.x;
    const int lane = tid & 63, wave = tid >> 6;
    const int q = lane >> 4, l16 = lane & 15;
    const int wm = (wave >> 2) << 7;   // 0 or 128 (M half)
    const int wn = (wave & 3) << 6;    // 0/64/128/192 (N quarter)
    const int tileM = blockIdx.y << 8, tileN = blockIdx.x << 8;

    f32x4 acc[8][4];
#pragma unroll
    for (int i = 0; i < 8; i++)
#pragma unroll
        for (int j = 0; j < 4; j++) acc[i][j] = (f32x4){0.f, 0.f, 0.f, 0.f};

    const int srow = tid >> 3;          // 0..63
    const int scol = (tid & 7) << 3;    // 0..56
    const unsigned short* pA[4];
    const unsigned short* pB[4];
#pragma unroll
    for (int j = 0; j < 4; j++) {
        int ra = tileM + j * 64 + srow; if (ra > MROWS - 1) ra = MROWS - 1;
        pA[j] = A + (size_t)ra * K + scol;
        pB[j] = W + (size_t)(tileN + j * 64 + srow) * Wstride + scol;
    }

    auto STAGE = [&](int buf, int k0) {
#pragma unroll
        for (int j = 0; j < 4; j++) {
            gl2lds(pA[j] + k0, &Alds[buf][j * 4096 + wave * 512]);
            gl2lds(pB[j] + k0, &Blds[buf][j * 4096 + wave * 512]);
        }
    };

    auto COMPUTE = [&](int buf) {
#pragma unroll
        for (int ks = 0; ks < 2; ks++) {
            bf16x8 af[8], bfr[4];
#pragma unroll
            for (int mi = 0; mi < 8; mi++)
                af[mi] = ld_bf8(&Alds[buf][(wm + mi * 16 + l16) * 64 + ks * 32 + q * 8]);
#pragma unroll
            for (int ni = 0; ni < 4; ni++)
                bfr[ni] = ld_bf8(&Blds[buf][(wn + ni * 16 + l16) * 64 + ks * 32 + q * 8]);
#pragma unroll
            for (int mi = 0; mi < 8; mi++)
#pragma unroll
                for (int ni = 0; ni < 4; ni++)
                    acc[mi][ni] = __builtin_amdgcn_mfma_f32_16x16x32_bf16(af[mi], bfr[ni], acc[mi][ni], 0, 0, 0);
        }
    };

    const int NT = K >> 6;
    STAGE(0, 0);
    __syncthreads();
    int cur = 0;
    for (int t = 0; t < NT; ++t) {
        if (t + 1 < NT) STAGE(cur ^ 1, (t + 1) << 6);
        COMPUTE(cur);
        __syncthreads();
        cur ^= 1;
    }

#pragma unroll
    for (int mi = 0; mi < 8; mi++) {
#pragma unroll
        for (int r = 0; r < 4; r++) {
            int row = tileM + wm + mi * 16 + q * 4 + r;
            if (row >= MROWS) continue;
            unsigned int bb = 0, nn = 0;
            if constexpr (OP == 0) {
                bb = ((unsigned int)row * 58154u) >> 25;   // row/577, exact for row<78766
                nn = (unsigned int)row - bb * 577u;
            }
#pragma unroll
            for (int ni = 0; ni < 4; ni++) {
                int col = tileN + wn + ni * 16 + l16;
                size_t oidx = (size_t)row * Nout + col;
                float v = acc[mi][ni][r] + bf2f(bias[col]);
                if constexpr (OP == 0) {
                    int s = col >> 10, h = (col >> 6) & 15, d = col & 63;
                    size_t bh = (size_t)(bb * 16 + h);
                    if (s == 0)      ((unsigned short*)Out )[(bh * NTOK + nn) * 64 + d] = f2bf(v * QSCALE);
                    else if (s == 1) ((unsigned short*)Out2)[(bh * NTOK + nn) * 64 + d] = f2bf(v);
                    else             ((unsigned short*)Out3)[(bh * 64 + d) * NPADV + nn] = f2bf(v);
                } else {  // OP == 2
                    ((unsigned short*)Out)[oidx] = f2bf(gelu_f(v));
                }
            }
        }
    }
}

// ---------------- Flash attention, no-max unnormalized softmax ----------------
__global__ __launch_bounds__(256) void attn_kernel(
    const unsigned short* __restrict__ Qb,
    const unsigned short* __restrict__ Kb,
    const unsigned short* __restrict__ Vt,
    unsigned short* __restrict__ o)
{
    const int flat = blockIdx.x;
    const int x8 = flat & 7;
    const int g = flat >> 3;
    const int qt = g % 10;
    const int bh = (g / 10) * 8 + x8;      // b*16 + h
    const int q0 = qt * 64;
    const int tid = threadIdx.x;
    const int wv = tid >> 6, lane = tid & 63;
    const int qd = lane >> 4, l16 = lane & 15;

    __shared__ __align__(16) unsigned short Ps[4][16 * 72];

    const unsigned short* Qh = Qb + (size_t)bh * NTOK * 64;
    const unsigned short* Kh = Kb + (size_t)bh * NTOK * 64;
    const unsigned short* Vh = Vt + (size_t)bh * 64 * NPADV;

    int qrow = q0 + wv * 16 + l16;
    int qr = qrow < NTOK ? qrow : NTOK - 1;
    bf16x8 qf0 = ld_bf8(Qh + (size_t)qr * 64 + qd * 8);
    bf16x8 qf1 = ld_bf8(Qh + (size_t)qr * 64 + 32 + qd * 8);

    float lsum[4];
    f32x4 Oacc[4];
#pragma unroll
    for (int r = 0; r < 4; r++) lsum[r] = 0.f;
#pragma unroll
    for (int ni = 0; ni < 4; ni++) Oacc[ni] = (f32x4){0.f, 0.f, 0.f, 0.f};

    for (int kt = 0; kt < 10; kt++) {
        const int k0 = kt * 64;
        const bool tail = (kt == 9);
        f32x4 sacc[4];
#pragma unroll
        for (int ni = 0; ni < 4; ni++) sacc[ni] = (f32x4){0.f, 0.f, 0.f, 0.f};
#pragma unroll
        for (int ni = 0; ni < 4; ni++) {
            int krow = k0 + ni * 16 + l16;
            if (krow > NTOK - 1) krow = NTOK - 1;
            const unsigned short* kp = Kh + (size_t)krow * 64 + qd * 8;
            bf16x8 b0 = ld_bf8(kp);
            bf16x8 b1 = ld_bf8(kp + 32);
            sacc[ni] = __builtin_amdgcn_mfma_f32_16x16x32_bf16(qf0, b0, sacc[ni], 0, 0, 0);
            sacc[ni] = __builtin_amdgcn_mfma_f32_16x16x32_bf16(qf1, b1, sacc[ni], 0, 0, 0);
        }

#pragma unroll
        for (int r = 0; r < 4; r++) {
#pragma unroll
            for (int ni = 0; ni < 4; ni++) {
                float pv = exp2f(sacc[ni][r]);
                if (tail && (k0 + ni * 16 + l16 >= NTOK)) pv = 0.f;
                lsum[r] += pv;
                Ps[wv][(qd * 4 + r) * 72 + ni * 16 + l16] = f2bf(pv);
            }
        }

#pragma unroll
        for (int kk = 0; kk < 2; kk++) {
            bf16x8 a = ld_bf8(&Ps[wv][l16 * 72 + kk * 32 + qd * 8]);
            int kchunk = k0 + kk * 32 + qd * 8;
            if (kchunk > NTOK - 1) kchunk = NTOK - 1;  // clamped chunks have P==0
#pragma unroll
            for (int ni = 0; ni < 4; ni++) {
                bf16x8 bb = ld_bf8(Vh + (size_t)(ni * 16 + l16) * NPADV + kchunk);
                Oacc[ni] = __builtin_amdgcn_mfma_f32_16x16x32_bf16(a, bb, Oacc[ni], 0, 0, 0);
            }
        }
    }

#pragma unroll
    for (int r = 0; r < 4; r++)
#pragma unroll
        for (int off = 8; off > 0; off >>= 1) lsum[r] += __shfl_xor(lsum[r], off);

    const int b = bh >> 4, h = bh & 15;
#pragma unroll
    for (int r = 0; r < 4; r++) {
        int gq = q0 + wv * 16 + qd * 4 + r;
        if (gq >= NTOK) continue;
        float inv = 1.0f / lsum[r];
#pragma unroll
        for (int ni = 0; ni < 4; ni++) {
            int d = ni * 16 + l16;
            o[((size_t)b * NTOK + gq) * CDIM + (size_t)h * 64 + d] = f2bf(Oacc[ni][r] * inv);
        }
    }
}

// ---------------- launch ----------------
extern "C" void kernel_launch(void* const* d_in, const int* in_sizes, int n_in,
                              void* d_out, int out_size, void* d_ws, size_t ws_size,
                              hipStream_t stream) {
    (void)in_sizes; (void)n_in; (void)out_size;
    const float* x      = (const float*)d_in[0];
    const float* ln1_w  = (const float*)d_in[1];
    const float* ln1_b  = (const float*)d_in[2];
    const float* qkv_w  = (const float*)d_in[3];
    const float* qkv_b  = (const float*)d_in[4];
    const float* proj_w = (const float*)d_in[5];
    const float* proj_b = (const float*)d_in[6];
    const float* ln2_w  = (const float*)d_in[7];
    const float* ln2_b  = (const float*)d_in[8];
    const float* fc1_w  = (const float*)d_in[9];
    const float* fc1_b  = (const float*)d_in[10];
    const float* fc2_w  = (const float*)d_in[11];
    const float* fc2_b  = (const float*)d_in[12];

    // ---- ws layout: converted weights, then big regions ----
    char* ws = (char*)d_ws;
    size_t off = 0;
    auto alloc = [&](size_t els) { void* p = ws + off; off += els * 2; return (unsigned short*)p; };
    unsigned short* qkvw_b  = alloc(3145728);
    unsigned short* projw_b = alloc(1048576);
    unsigned short* fc1w_b  = alloc(4194304);
    unsigned short* fc2w_b  = alloc(4194304);
    unsigned short* qkvb_b  = alloc(3072);
    unsigned short* projb_b = alloc(1024);
    unsigned short* fc1b_b  = alloc(4096);
    unsigned short* fc2b_b  = alloc(1024);
    off = (off + 255) & ~(size_t)255;
    unsigned short* R1 = (unsigned short*)(ws + off); off += (size_t)MROWS * 1024 * 2;          // Kb -> x1
    unsigned short* R2 = (unsigned short*)(ws + off); off += (size_t)512 * 64 * NPADV * 2;      // Vt -> h2
    unsigned short* R3 = (unsigned short*)(ws + off);                                           // fc1 out
    size_t rem = ws_size > off ? ws_size - off : 0;
    const int CH = rem >= (size_t)MROWS * H4DIM * 2 ? H4DIM
                 : (rem >= (size_t)MROWS * 1024 * 2 ? 1024
                 : (rem >= (size_t)MROWS * 512 * 2 ? 512 : 256));

    // d_out (f32 [M,1024] = 75.6MB) used as scratch: half1 = Qb, half2 = h1 then obuf
    unsigned short* Qb   = (unsigned short*)d_out;
    unsigned short* h1   = Qb + (size_t)MROWS * 1024;
    unsigned short* obuf = h1;
    unsigned short* Kb = R1;
    unsigned short* Vt = R2;
    unsigned short* x1 = R1;
    unsigned short* h2 = R2;

    // weight/bias conversion (every call; graph-safe)
    conv_kernel<<<3145728 / 1024, 256, 0, stream>>>(qkv_w,  qkvw_b,  3145728);
    conv_kernel<<<1048576 / 1024, 256, 0, stream>>>(proj_w, projw_b, 1048576);
    conv_kernel<<<4194304 / 1024, 256, 0, stream>>>(fc1_w,  fc1w_b,  4194304);
    conv_kernel<<<4194304 / 1024, 256, 0, stream>>>(fc2_w,  fc2w_b,  4194304);
    conv_kernel<<<3, 256, 0, stream>>>(qkv_b,  qkvb_b,  3072);
    conv_kernel<<<1, 256, 0, stream>>>(proj_b, projb_b, 1024);
    conv_kernel<<<4, 256, 0, stream>>>(fc1_b,  fc1b_b,  4096);
    conv_kernel<<<1, 256, 0, stream>>>(fc2_b,  fc2b_b,  1024);

    const int mt128 = (MROWS + 127) / 128;  // 145
    const int mt256 = (MROWS + 255) / 256;  // 73

    // h1 = LN1(x)
    ln_kernel<true><<<MROWS, 256, 0, stream>>>(x, ln1_w, ln1_b, h1);
    // qkv GEMM -> split Qb/Kb/Vt  (N=3072: 876 blocks, 256-tile packs OK)
    gemm256<0><<<dim3(C3DIM / 256, mt256), 512, 0, stream>>>(
        h1, qkvw_b, CDIM, qkvb_b, Qb, Kb, Vt, CDIM, C3DIM);
    // attention -> obuf (overwrites h1; h1 dead)
    attn_kernel<<<5120, 256, 0, stream>>>(Qb, Kb, Vt, obuf);
    // x1 = bf16(x + obuf @ proj_w^T + proj_b)   (N=1024: 128-tile for packing)
    gemm128<1><<<dim3(CDIM / 128, mt128), 256, 0, stream>>>(
        obuf, projw_b, CDIM, projb_b, x, x1, CDIM, CDIM);
    // h2 = LN2(x1)   (Vt dead)
    ln_kernel<false><<<MROWS, 256, 0, stream>>>(x1, ln2_w, ln2_b, h2);

    if (CH == H4DIM) {
        // fc1 (N=4096: 1168 blocks, 256-tile packs OK)
        gemm256<2><<<dim3(H4DIM / 256, mt256), 512, 0, stream>>>(
            h2, fc1w_b, CDIM, fc1b_b, R3, nullptr, nullptr, CDIM, H4DIM);
        // fc2 (N=1024: 128-tile for packing; K=4096 amortizes 2-barrier stall)
        gemm128<3><<<dim3(CDIM / 128, mt128), 256, 0, stream>>>(
            R3, fc2w_b, H4DIM, fc2b_b, x1, d_out, H4DIM, CDIM);
    } else {
        for (int c0 = 0; c0 < H4DIM; c0 += CH) {
            gemm256<2><<<dim3(CH / 256, mt256), 512, 0, stream>>>(
                h2, fc1w_b + (size_t)c0 * CDIM, CDIM, fc1b_b + c0, R3, nullptr, nullptr, CDIM, CH);
            if (c0 == 0)
                gemm128<3><<<dim3(CDIM / 128, mt128), 256, 0, stream>>>(
                    R3, fc2w_b, H4DIM, fc2b_b, x1, d_out, CH, CDIM);
            else
                gemm128<4><<<dim3(CDIM / 128, mt128), 256, 0, stream>>>(
                    R3, fc2w_b + c0, H4DIM, nullptr, nullptr, d_out, CH, CDIM);
        }
    }
}

// Round 3
// 1208.543 us; speedup vs baseline: 1.0701x; 1.0174x over previous
//
#include <hip/hip_runtime.h>
#include <math.h>

// ---- problem constants ----
#define BATCH  32
#define NTOK   577
#define CDIM   1024
#define C3DIM  3072
#define H4DIM  4096
#define NHEAD  16
#define MROWS  (BATCH * NTOK)   // 18464
#define NPADV  584              // 577 rounded up to 8 (V^T row pad)

typedef __bf16 bf16x8 __attribute__((ext_vector_type(8)));
typedef float  f32x4  __attribute__((ext_vector_type(4)));
typedef unsigned short u16x8 __attribute__((ext_vector_type(8)));

__device__ __forceinline__ float bf2f(unsigned short u) {
    union { unsigned int i; float f; } v; v.i = ((unsigned int)u) << 16; return v.f;
}
__device__ __forceinline__ unsigned short f2bf(float f) {
    union { float f; unsigned int i; } v; v.f = f;
    unsigned int r = v.i + 0x7FFFu + ((v.i >> 16) & 1u);
    return (unsigned short)(r >> 16);
}
__device__ __forceinline__ bf16x8 ld_bf8(const unsigned short* p) {
    return __builtin_bit_cast(bf16x8, *(const u16x8*)p);
}

// async global->LDS, 16B per lane. LDS dest = wave-uniform base + lane*16.
typedef const __attribute__((address_space(1))) unsigned int* gptr_t;
typedef __attribute__((address_space(3))) unsigned int* lptr_t;
__device__ __forceinline__ void gl2lds(const void* g, const void* l) {
    __builtin_amdgcn_global_load_lds(
        (gptr_t)(unsigned long long)g,
        (lptr_t)(unsigned int)(unsigned long long)l,
        16, 0, 0);
}

// Bijective chunked XCD remap (m204): blocks round-robin across 8 XCDs by
// hardware flat index; give each XCD a CONTIGUOUS chunk of the logical
// (N-fastest) tile order so all N-tiles of one A-row run on ONE XCD ->
// the A row-tile is fetched into that XCD's L2 once, not 8-16 times.
__device__ __forceinline__ int xcd_chunk_logical(int orig, int nwg) {
    int xcd = orig & 7, k = orig >> 3;
    int q = nwg >> 3, r = nwg & 7;
    int base = xcd < r ? xcd * (q + 1) : r * (q + 1) + (xcd - r) * q;
    return base + k;
}

// Q pre-scale: Dh^-0.5 * log2(e), so softmax runs in exp2 domain
#define QSCALE 0.18033688011112042f

// GELU tanh-form in exp2 domain: max |err| vs erf-GELU ~3e-4 << bf16 noise.
__device__ __forceinline__ float gelu_f(float v) {
    float z = exp2f(v * fmaf(v * v, 0.1029432f, 2.3022082f));
    return v - v * __builtin_amdgcn_rcpf(1.0f + z);
}

// ---------------- f32 -> bf16 convert ----------------
__global__ __launch_bounds__(256) void conv_kernel(const float* __restrict__ src,
                                                   unsigned short* __restrict__ dst, int n) {
    int i = (blockIdx.x * 256 + threadIdx.x) * 4;
    if (i < n) {
        float4 v = *(const float4*)(src + i);
        dst[i]     = f2bf(v.x);
        dst[i + 1] = f2bf(v.y);
        dst[i + 2] = f2bf(v.z);
        dst[i + 3] = f2bf(v.w);
    }
}

// ---------------- LayerNorm ----------------
template<bool F32IN>
__global__ __launch_bounds__(256) void ln_kernel(
    const void* __restrict__ X,
    const float* __restrict__ w,
    const float* __restrict__ b,
    unsigned short* __restrict__ out)
{
    const int row = blockIdx.x;
    const int t = threadIdx.x;
    float vals[4]; float s = 0.f, ss = 0.f;
#pragma unroll
    for (int i = 0; i < 4; i++) {
        int c = t + i * 256;
        float v;
        if (F32IN) v = ((const float*)X)[(size_t)row * CDIM + c];
        else       v = bf2f(((const unsigned short*)X)[(size_t)row * CDIM + c]);
        vals[i] = v; s += v; ss += v * v;
    }
#pragma unroll
    for (int off = 32; off > 0; off >>= 1) { s += __shfl_xor(s, off); ss += __shfl_xor(ss, off); }
    __shared__ float red[8];
    if ((t & 63) == 0) { red[t >> 6] = s; red[4 + (t >> 6)] = ss; }
    __syncthreads();
    s  = red[0] + red[1] + red[2] + red[3];
    ss = red[4] + red[5] + red[6] + red[7];
    float mu  = s * (1.f / CDIM);
    float var = ss * (1.f / CDIM) - mu * mu;
    float rs  = rsqrtf(var + 1e-6f);
#pragma unroll
    for (int i = 0; i < 4; i++) {
        int c = t + i * 256;
        float o = (vals[i] - mu) * rs * w[c] + b[c];
        out[(size_t)row * CDIM + c] = f2bf(o);
    }
}

// ============ GEMM A: 128x128 tile, BK=32, 4 waves, 16 KiB LDS ============
// High-occupancy variant: for N=1024 GEMMs (1160 blocks, ~95% CU packing).
// 1D grid, XCD-chunked: logical tile order is N-fastest, so one XCD runs all
// 8 N-tiles of an A-row back-to-back -> A-row L2-resident (fc2's A is 151 MB;
// round-robin placement re-fetched it ~4x from HBM = 674 MB, the r2 bottleneck).
// OP=1: +bias, + f32 residual (Res=x), bf16 out (x1)
// OP=3: +bias, + bf16 residual (x1), f32 out to d_out
// OP=4: f32 accumulate into d_out (no bias)
template<int OP>
__global__ __launch_bounds__(256) void gemm128(
    const unsigned short* __restrict__ A,
    const unsigned short* __restrict__ W, int Wstride,
    const unsigned short* __restrict__ bias,
    const void* __restrict__ Res,
    void* __restrict__ Out,
    int K, int Nout, int ntn)
{
    __shared__ __align__(16) unsigned short Alds[128 * 32];
    __shared__ __align__(16) unsigned short Blds[128 * 32];
    const int tid  = threadIdx.x;
    const int lane = tid & 63, wave = tid >> 6;
    const int q = lane >> 4, l16 = lane & 15;
    const int wm = (wave & 1) << 6, wn = (wave >> 1) << 6;

    const int logical = xcd_chunk_logical(blockIdx.x, gridDim.x);
    const int tileM = (logical / ntn) << 7;
    const int tileN = (logical % ntn) << 7;

    f32x4 acc[4][4];
#pragma unroll
    for (int i = 0; i < 4; i++)
#pragma unroll
        for (int j = 0; j < 4; j++) acc[i][j] = (f32x4){0.f, 0.f, 0.f, 0.f};

    const int srow = tid >> 2;
    const int soff = (tid & 3) << 3;
    int arow1 = tileM + srow;       if (arow1 > MROWS - 1) arow1 = MROWS - 1;
    int arow2 = tileM + srow + 64;  if (arow2 > MROWS - 1) arow2 = MROWS - 1;
    const unsigned short* Aptr  = A + (size_t)arow1 * K + soff;
    const unsigned short* Aptr2 = A + (size_t)arow2 * K + soff;
    const unsigned short* Wp    = W + (size_t)(tileN + srow) * Wstride + soff;
    const unsigned short* Wp2   = Wp + (size_t)64 * Wstride;

    for (int k0 = 0; k0 < K; k0 += 32) {
        __syncthreads();   // all reads of previous tile complete
        gl2lds(Aptr  + k0, &Alds[wave * 512]);
        gl2lds(Aptr2 + k0, &Alds[2048 + wave * 512]);
        gl2lds(Wp    + k0, &Blds[wave * 512]);
        gl2lds(Wp2   + k0, &Blds[2048 + wave * 512]);
        __syncthreads();   // drains vmcnt -> LDS populated
        bf16x8 af[4], bfr[4];
#pragma unroll
        for (int mi = 0; mi < 4; mi++) af[mi]  = ld_bf8(&Alds[(wm + mi * 16 + l16) * 32 + q * 8]);
#pragma unroll
        for (int ni = 0; ni < 4; ni++) bfr[ni] = ld_bf8(&Blds[(wn + ni * 16 + l16) * 32 + q * 8]);
#pragma unroll
        for (int mi = 0; mi < 4; mi++)
#pragma unroll
            for (int ni = 0; ni < 4; ni++)
                acc[mi][ni] = __builtin_amdgcn_mfma_f32_16x16x32_bf16(af[mi], bfr[ni], acc[mi][ni], 0, 0, 0);
    }

#pragma unroll
    for (int mi = 0; mi < 4; mi++) {
#pragma unroll
        for (int r = 0; r < 4; r++) {
            int row = tileM + wm + mi * 16 + q * 4 + r;
            if (row >= MROWS) continue;
#pragma unroll
            for (int ni = 0; ni < 4; ni++) {
                int col = tileN + wn + ni * 16 + l16;
                size_t oidx = (size_t)row * Nout + col;
                float v = acc[mi][ni][r];
                if constexpr (OP != 4) v += bf2f(bias[col]);
                if constexpr (OP == 1) {
                    v += ((const float*)Res)[oidx];
                    ((unsigned short*)Out)[oidx] = f2bf(v);
                } else if constexpr (OP == 3) {
                    v += bf2f(((const unsigned short*)Res)[oidx]);
                    ((float*)Out)[oidx] = v;
                } else {
                    ((float*)Out)[oidx] += v;
                }
            }
        }
    }
}

// ============ GEMM B: 256x256 tile, BK=64, 8 waves, 2-phase prefetch ========
// 1 block/CU (128 KiB LDS). For large-N GEMMs (qkv 876 blocks, fc1 1168).
// Same XCD-chunked 1D grid (A re-read 12x/16x otherwise).
// OP=0: +bias, qkv split-scatter (Out=Qb *QSCALE, Out2=Kb, Out3=Vt transposed)
// OP=2: +bias, GELU, bf16 out (fc1)
template<int OP>
__global__ __launch_bounds__(512, 2) void gemm256(
    const unsigned short* __restrict__ A,
    const unsigned short* __restrict__ W, int Wstride,
    const unsigned short* __restrict__ bias,
    void* __restrict__ Out,
    void* __restrict__ Out2,
    void* __restrict__ Out3,
    int K, int Nout, int ntn)
{
    __shared__ __align__(16) unsigned short Alds[2][256 * 64];
    __shared__ __align__(16) unsigned short Blds[2][256 * 64];

    const int tid  = threadIdx.x;
    const int lane = tid & 63, wave = tid >> 6;
    const int q = lane >> 4, l16 = lane & 15;
    const int wm = (wave >> 2) << 7;   // 0 or 128 (M half)
    const int wn = (wave & 3) << 6;    // 0/64/128/192 (N quarter)

    const int logical = xcd_chunk_logical(blockIdx.x, gridDim.x);
    const int tileM = (logical / ntn) << 8;
    const int tileN = (logical % ntn) << 8;

    f32x4 acc[8][4];
#pragma unroll
    for (int i = 0; i < 8; i++)
#pragma unroll
        for (int j = 0; j < 4; j++) acc[i][j] = (f32x4){0.f, 0.f, 0.f, 0.f};

    const int srow = tid >> 3;          // 0..63
    const int scol = (tid & 7) << 3;    // 0..56
    const unsigned short* pA[4];
    const unsigned short* pB[4];
#pragma unroll
    for (int j = 0; j < 4; j++) {
        int ra = tileM + j * 64 + srow; if (ra > MROWS - 1) ra = MROWS - 1;
        pA[j] = A + (size_t)ra * K + scol;
        pB[j] = W + (size_t)(tileN + j * 64 + srow) * Wstride + scol;
    }

    auto STAGE = [&](int buf, int k0) {
#pragma unroll
        for (int j = 0; j < 4; j++) {
            gl2lds(pA[j] + k0, &Alds[buf][j * 4096 + wave * 512]);
            gl2lds(pB[j] + k0, &Blds[buf][j * 4096 + wave * 512]);
        }
    };

    auto COMPUTE = [&](int buf) {
#pragma unroll
        for (int ks = 0; ks < 2; ks++) {
            bf16x8 af[8], bfr[4];
#pragma unroll
            for (int mi = 0; mi < 8; mi++)
                af[mi] = ld_bf8(&Alds[buf][(wm + mi * 16 + l16) * 64 + ks * 32 + q * 8]);
#pragma unroll
            for (int ni = 0; ni < 4; ni++)
                bfr[ni] = ld_bf8(&Blds[buf][(wn + ni * 16 + l16) * 64 + ks * 32 + q * 8]);
#pragma unroll
            for (int mi = 0; mi < 8; mi++)
#pragma unroll
                for (int ni = 0; ni < 4; ni++)
                    acc[mi][ni] = __builtin_amdgcn_mfma_f32_16x16x32_bf16(af[mi], bfr[ni], acc[mi][ni], 0, 0, 0);
        }
    };

    const int NT = K >> 6;
    STAGE(0, 0);
    __syncthreads();
    int cur = 0;
    for (int t = 0; t < NT; ++t) {
        if (t + 1 < NT) STAGE(cur ^ 1, (t + 1) << 6);
        COMPUTE(cur);
        __syncthreads();
        cur ^= 1;
    }

#pragma unroll
    for (int mi = 0; mi < 8; mi++) {
#pragma unroll
        for (int r = 0; r < 4; r++) {
            int row = tileM + wm + mi * 16 + q * 4 + r;
            if (row >= MROWS) continue;
            unsigned int bb = 0, nn = 0;
            if constexpr (OP == 0) {
                bb = ((unsigned int)row * 58154u) >> 25;   // row/577, exact for row<78766
                nn = (unsigned int)row - bb * 577u;
            }
#pragma unroll
            for (int ni = 0; ni < 4; ni++) {
                int col = tileN + wn + ni * 16 + l16;
                size_t oidx = (size_t)row * Nout + col;
                float v = acc[mi][ni][r] + bf2f(bias[col]);
                if constexpr (OP == 0) {
                    int s = col >> 10, h = (col >> 6) & 15, d = col & 63;
                    size_t bh = (size_t)(bb * 16 + h);
                    if (s == 0)      ((unsigned short*)Out )[(bh * NTOK + nn) * 64 + d] = f2bf(v * QSCALE);
                    else if (s == 1) ((unsigned short*)Out2)[(bh * NTOK + nn) * 64 + d] = f2bf(v);
                    else             ((unsigned short*)Out3)[(bh * 64 + d) * NPADV + nn] = f2bf(v);
                } else {  // OP == 2
                    ((unsigned short*)Out)[oidx] = f2bf(gelu_f(v));
                }
            }
        }
    }
}

// ---------------- Flash attention, no-max unnormalized softmax ----------------
__global__ __launch_bounds__(256) void attn_kernel(
    const unsigned short* __restrict__ Qb,
    const unsigned short* __restrict__ Kb,
    const unsigned short* __restrict__ Vt,
    unsigned short* __restrict__ o)
{
    const int flat = blockIdx.x;
    const int x8 = flat & 7;
    const int g = flat >> 3;
    const int qt = g % 10;
    const int bh = (g / 10) * 8 + x8;      // b*16 + h
    const int q0 = qt * 64;
    const int tid = threadIdx.x;
    const int wv = tid >> 6, lane = tid & 63;
    const int qd = lane >> 4, l16 = lane & 15;

    __shared__ __align__(16) unsigned short Ps[4][16 * 72];

    const unsigned short* Qh = Qb + (size_t)bh * NTOK * 64;
    const unsigned short* Kh = Kb + (size_t)bh * NTOK * 64;
    const unsigned short* Vh = Vt + (size_t)bh * 64 * NPADV;

    int qrow = q0 + wv * 16 + l16;
    int qr = qrow < NTOK ? qrow : NTOK - 1;
    bf16x8 qf0 = ld_bf8(Qh + (size_t)qr * 64 + qd * 8);
    bf16x8 qf1 = ld_bf8(Qh + (size_t)qr * 64 + 32 + qd * 8);

    float lsum[4];
    f32x4 Oacc[4];
#pragma unroll
    for (int r = 0; r < 4; r++) lsum[r] = 0.f;
#pragma unroll
    for (int ni = 0; ni < 4; ni++) Oacc[ni] = (f32x4){0.f, 0.f, 0.f, 0.f};

    for (int kt = 0; kt < 10; kt++) {
        const int k0 = kt * 64;
        const bool tail = (kt == 9);
        f32x4 sacc[4];
#pragma unroll
        for (int ni = 0; ni < 4; ni++) sacc[ni] = (f32x4){0.f, 0.f, 0.f, 0.f};
#pragma unroll
        for (int ni = 0; ni < 4; ni++) {
            int krow = k0 + ni * 16 + l16;
            if (krow > NTOK - 1) krow = NTOK - 1;
            const unsigned short* kp = Kh + (size_t)krow * 64 + qd * 8;
            bf16x8 b0 = ld_bf8(kp);
            bf16x8 b1 = ld_bf8(kp + 32);
            sacc[ni] = __builtin_amdgcn_mfma_f32_16x16x32_bf16(qf0, b0, sacc[ni], 0, 0, 0);
            sacc[ni] = __builtin_amdgcn_mfma_f32_16x16x32_bf16(qf1, b1, sacc[ni], 0, 0, 0);
        }

#pragma unroll
        for (int r = 0; r < 4; r++) {
#pragma unroll
            for (int ni = 0; ni < 4; ni++) {
                float pv = exp2f(sacc[ni][r]);
                if (tail && (k0 + ni * 16 + l16 >= NTOK)) pv = 0.f;
                lsum[r] += pv;
                Ps[wv][(qd * 4 + r) * 72 + ni * 16 + l16] = f2bf(pv);
            }
        }

#pragma unroll
        for (int kk = 0; kk < 2; kk++) {
            bf16x8 a = ld_bf8(&Ps[wv][l16 * 72 + kk * 32 + qd * 8]);
            int kchunk = k0 + kk * 32 + qd * 8;
            if (kchunk > NTOK - 1) kchunk = NTOK - 1;  // clamped chunks have P==0
#pragma unroll
            for (int ni = 0; ni < 4; ni++) {
                bf16x8 bb = ld_bf8(Vh + (size_t)(ni * 16 + l16) * NPADV + kchunk);
                Oacc[ni] = __builtin_amdgcn_mfma_f32_16x16x32_bf16(a, bb, Oacc[ni], 0, 0, 0);
            }
        }
    }

#pragma unroll
    for (int r = 0; r < 4; r++)
#pragma unroll
        for (int off = 8; off > 0; off >>= 1) lsum[r] += __shfl_xor(lsum[r], off);

    const int b = bh >> 4, h = bh & 15;
#pragma unroll
    for (int r = 0; r < 4; r++) {
        int gq = q0 + wv * 16 + qd * 4 + r;
        if (gq >= NTOK) continue;
        float inv = 1.0f / lsum[r];
#pragma unroll
        for (int ni = 0; ni < 4; ni++) {
            int d = ni * 16 + l16;
            o[((size_t)b * NTOK + gq) * CDIM + (size_t)h * 64 + d] = f2bf(Oacc[ni][r] * inv);
        }
    }
}

// ---------------- launch ----------------
extern "C" void kernel_launch(void* const* d_in, const int* in_sizes, int n_in,
                              void* d_out, int out_size, void* d_ws, size_t ws_size,
                              hipStream_t stream) {
    (void)in_sizes; (void)n_in; (void)out_size;
    const float* x      = (const float*)d_in[0];
    const float* ln1_w  = (const float*)d_in[1];
    const float* ln1_b  = (const float*)d_in[2];
    const float* qkv_w  = (const float*)d_in[3];
    const float* qkv_b  = (const float*)d_in[4];
    const float* proj_w = (const float*)d_in[5];
    const float* proj_b = (const float*)d_in[6];
    const float* ln2_w  = (const float*)d_in[7];
    const float* ln2_b  = (const float*)d_in[8];
    const float* fc1_w  = (const float*)d_in[9];
    const float* fc1_b  = (const float*)d_in[10];
    const float* fc2_w  = (const float*)d_in[11];
    const float* fc2_b  = (const float*)d_in[12];

    // ---- ws layout: converted weights, then big regions ----
    char* ws = (char*)d_ws;
    size_t off = 0;
    auto alloc = [&](size_t els) { void* p = ws + off; off += els * 2; return (unsigned short*)p; };
    unsigned short* qkvw_b  = alloc(3145728);
    unsigned short* projw_b = alloc(1048576);
    unsigned short* fc1w_b  = alloc(4194304);
    unsigned short* fc2w_b  = alloc(4194304);
    unsigned short* qkvb_b  = alloc(3072);
    unsigned short* projb_b = alloc(1024);
    unsigned short* fc1b_b  = alloc(4096);
    unsigned short* fc2b_b  = alloc(1024);
    off = (off + 255) & ~(size_t)255;
    unsigned short* R1 = (unsigned short*)(ws + off); off += (size_t)MROWS * 1024 * 2;          // Kb -> x1
    unsigned short* R2 = (unsigned short*)(ws + off); off += (size_t)512 * 64 * NPADV * 2;      // Vt -> h2
    unsigned short* R3 = (unsigned short*)(ws + off);                                           // fc1 out
    size_t rem = ws_size > off ? ws_size - off : 0;
    const int CH = rem >= (size_t)MROWS * H4DIM * 2 ? H4DIM
                 : (rem >= (size_t)MROWS * 1024 * 2 ? 1024
                 : (rem >= (size_t)MROWS * 512 * 2 ? 512 : 256));

    // d_out (f32 [M,1024] = 75.6MB) used as scratch: half1 = Qb, half2 = h1 then obuf
    unsigned short* Qb   = (unsigned short*)d_out;
    unsigned short* h1   = Qb + (size_t)MROWS * 1024;
    unsigned short* obuf = h1;
    unsigned short* Kb = R1;
    unsigned short* Vt = R2;
    unsigned short* x1 = R1;
    unsigned short* h2 = R2;

    // weight/bias conversion (every call; graph-safe)
    conv_kernel<<<3145728 / 1024, 256, 0, stream>>>(qkv_w,  qkvw_b,  3145728);
    conv_kernel<<<1048576 / 1024, 256, 0, stream>>>(proj_w, projw_b, 1048576);
    conv_kernel<<<4194304 / 1024, 256, 0, stream>>>(fc1_w,  fc1w_b,  4194304);
    conv_kernel<<<4194304 / 1024, 256, 0, stream>>>(fc2_w,  fc2w_b,  4194304);
    conv_kernel<<<3, 256, 0, stream>>>(qkv_b,  qkvb_b,  3072);
    conv_kernel<<<1, 256, 0, stream>>>(proj_b, projb_b, 1024);
    conv_kernel<<<4, 256, 0, stream>>>(fc1_b,  fc1b_b,  4096);
    conv_kernel<<<1, 256, 0, stream>>>(fc2_b,  fc2b_b,  1024);

    const int mt128 = (MROWS + 127) / 128;  // 145
    const int mt256 = (MROWS + 255) / 256;  // 73

    // h1 = LN1(x)
    ln_kernel<true><<<MROWS, 256, 0, stream>>>(x, ln1_w, ln1_b, h1);
    // qkv GEMM -> split Qb/Kb/Vt  (N=3072: 876 blocks; 12 N-tiles/row on 1 XCD)
    gemm256<0><<<(C3DIM / 256) * mt256, 512, 0, stream>>>(
        h1, qkvw_b, CDIM, qkvb_b, Qb, Kb, Vt, CDIM, C3DIM, C3DIM / 256);
    // attention -> obuf (overwrites h1; h1 dead)
    attn_kernel<<<5120, 256, 0, stream>>>(Qb, Kb, Vt, obuf);
    // x1 = bf16(x + obuf @ proj_w^T + proj_b)
    gemm128<1><<<(CDIM / 128) * mt128, 256, 0, stream>>>(
        obuf, projw_b, CDIM, projb_b, x, x1, CDIM, CDIM, CDIM / 128);
    // h2 = LN2(x1)   (Vt dead)
    ln_kernel<false><<<MROWS, 256, 0, stream>>>(x1, ln2_w, ln2_b, h2);

    if (CH == H4DIM) {
        // fc1 (N=4096: 1168 blocks; 16 N-tiles/row on 1 XCD)
        gemm256<2><<<(H4DIM / 256) * mt256, 512, 0, stream>>>(
            h2, fc1w_b, CDIM, fc1b_b, R3, nullptr, nullptr, CDIM, H4DIM, H4DIM / 256);
        // fc2 (A = 151 MB R3: the XCD-chunking target; 8 N-tiles/row on 1 XCD)
        gemm128<3><<<(CDIM / 128) * mt128, 256, 0, stream>>>(
            R3, fc2w_b, H4DIM, fc2b_b, x1, d_out, H4DIM, CDIM, CDIM / 128);
    } else {
        for (int c0 = 0; c0 < H4DIM; c0 += CH) {
            gemm256<2><<<(CH / 256) * mt256, 512, 0, stream>>>(
                h2, fc1w_b + (size_t)c0 * CDIM, CDIM, fc1b_b + c0, R3, nullptr, nullptr, CDIM, CH, CH / 256);
            if (c0 == 0)
                gemm128<3><<<(CDIM / 128) * mt128, 256, 0, stream>>>(
                    R3, fc2w_b, H4DIM, fc2b_b, x1, d_out, CH, CDIM, CDIM / 128);
            else
                gemm128<4><<<(CDIM / 128) * mt128, 256, 0, stream>>>(
                    R3, fc2w_b + c0, H4DIM, nullptr, nullptr, d_out, CH, CDIM, CDIM / 128);
        }
    }
}

// Round 4
// 1156.786 us; speedup vs baseline: 1.1180x; 1.0447x over previous
//
#include <hip/hip_runtime.h>
#include <math.h>

// ---- problem constants ----
#define BATCH  32
#define NTOK   577
#define CDIM   1024
#define C3DIM  3072
#define H4DIM  4096
#define NHEAD  16
#define MROWS  (BATCH * NTOK)   // 18464
#define NPADV  584              // 577 rounded up to 8 (V^T row pad)

typedef __bf16 bf16x8 __attribute__((ext_vector_type(8)));
typedef float  f32x4  __attribute__((ext_vector_type(4)));
typedef unsigned short u16x8 __attribute__((ext_vector_type(8)));

__device__ __forceinline__ float bf2f(unsigned short u) {
    union { unsigned int i; float f; } v; v.i = ((unsigned int)u) << 16; return v.f;
}
__device__ __forceinline__ unsigned short f2bf(float f) {
    union { float f; unsigned int i; } v; v.f = f;
    unsigned int r = v.i + 0x7FFFu + ((v.i >> 16) & 1u);
    return (unsigned short)(r >> 16);
}
__device__ __forceinline__ bf16x8 ld_bf8(const unsigned short* p) {
    return __builtin_bit_cast(bf16x8, *(const u16x8*)p);
}

// async global->LDS, 16B per lane. LDS dest = wave-uniform base + lane*16.
typedef const __attribute__((address_space(1))) unsigned int* gptr_t;
typedef __attribute__((address_space(3))) unsigned int* lptr_t;
__device__ __forceinline__ void gl2lds(const void* g, const void* l) {
    __builtin_amdgcn_global_load_lds(
        (gptr_t)(unsigned long long)g,
        (lptr_t)(unsigned int)(unsigned long long)l,
        16, 0, 0);
}

// Bijective chunked XCD remap (m204): blocks round-robin across 8 XCDs by
// hardware flat index; give each XCD a CONTIGUOUS chunk of the logical
// (N-fastest) tile order so all N-tiles of one A-row run on ONE XCD ->
// the A row-tile is fetched into that XCD's L2 once, not 8-16 times.
// (r3 verified: fc2 FETCH 674 MB -> 167 MB.)
__device__ __forceinline__ int xcd_chunk_logical(int orig, int nwg) {
    int xcd = orig & 7, k = orig >> 3;
    int q = nwg >> 3, r = nwg & 7;
    int base = xcd < r ? xcd * (q + 1) : r * (q + 1) + (xcd - r) * q;
    return base + k;
}

// Q pre-scale: Dh^-0.5 * log2(e), so softmax runs in exp2 domain
#define QSCALE 0.18033688011112042f

// GELU tanh-form in exp2 domain: max |err| vs erf-GELU ~3e-4 << bf16 noise.
__device__ __forceinline__ float gelu_f(float v) {
    float z = exp2f(v * fmaf(v * v, 0.1029432f, 2.3022082f));
    return v - v * __builtin_amdgcn_rcpf(1.0f + z);
}

// ---------------- f32 -> bf16 convert ----------------
__global__ __launch_bounds__(256) void conv_kernel(const float* __restrict__ src,
                                                   unsigned short* __restrict__ dst, int n) {
    int i = (blockIdx.x * 256 + threadIdx.x) * 4;
    if (i < n) {
        float4 v = *(const float4*)(src + i);
        dst[i]     = f2bf(v.x);
        dst[i + 1] = f2bf(v.y);
        dst[i + 2] = f2bf(v.z);
        dst[i + 3] = f2bf(v.w);
    }
}

// ---------------- LayerNorm ----------------
template<bool F32IN>
__global__ __launch_bounds__(256) void ln_kernel(
    const void* __restrict__ X,
    const float* __restrict__ w,
    const float* __restrict__ b,
    unsigned short* __restrict__ out)
{
    const int row = blockIdx.x;
    const int t = threadIdx.x;
    float vals[4]; float s = 0.f, ss = 0.f;
#pragma unroll
    for (int i = 0; i < 4; i++) {
        int c = t + i * 256;
        float v;
        if (F32IN) v = ((const float*)X)[(size_t)row * CDIM + c];
        else       v = bf2f(((const unsigned short*)X)[(size_t)row * CDIM + c]);
        vals[i] = v; s += v; ss += v * v;
    }
#pragma unroll
    for (int off = 32; off > 0; off >>= 1) { s += __shfl_xor(s, off); ss += __shfl_xor(ss, off); }
    __shared__ float red[8];
    if ((t & 63) == 0) { red[t >> 6] = s; red[4 + (t >> 6)] = ss; }
    __syncthreads();
    s  = red[0] + red[1] + red[2] + red[3];
    ss = red[4] + red[5] + red[6] + red[7];
    float mu  = s * (1.f / CDIM);
    float var = ss * (1.f / CDIM) - mu * mu;
    float rs  = rsqrtf(var + 1e-6f);
#pragma unroll
    for (int i = 0; i < 4; i++) {
        int c = t + i * 256;
        float o = (vals[i] - mu) * rs * w[c] + b[c];
        out[(size_t)row * CDIM + c] = f2bf(o);
    }
}

// ============ GEMM A: 128x128 tile, BK=32, 4 waves, 2-phase prefetch ========
// Double-buffered LDS (32 KiB), ONE barrier per K-step: STAGE tile t+1 while
// computing tile t. r3 showed the serial 2-barrier loop capped at ~560 TF busy
// (load latency exposed every K-step); prefetch removes it while keeping the
// 1160-block grid (~91% CU packing) that the 256-tile can't give at N=1024.
// OP=1: +bias, + f32 residual (Res=x), bf16 out (x1)
// OP=3: +bias, + bf16 residual (x1), f32 out to d_out
// OP=4: f32 accumulate into d_out (no bias)
template<int OP>
__global__ __launch_bounds__(256) void gemm128(
    const unsigned short* __restrict__ A,
    const unsigned short* __restrict__ W, int Wstride,
    const unsigned short* __restrict__ bias,
    const void* __restrict__ Res,
    void* __restrict__ Out,
    int K, int Nout, int ntn)
{
    __shared__ __align__(16) unsigned short Alds[2][128 * 32];
    __shared__ __align__(16) unsigned short Blds[2][128 * 32];
    const int tid  = threadIdx.x;
    const int lane = tid & 63, wave = tid >> 6;
    const int q = lane >> 4, l16 = lane & 15;
    const int wm = (wave & 1) << 6, wn = (wave >> 1) << 6;

    const int logical = xcd_chunk_logical(blockIdx.x, gridDim.x);
    const int tileM = (logical / ntn) << 7;
    const int tileN = (logical % ntn) << 7;

    f32x4 acc[4][4];
#pragma unroll
    for (int i = 0; i < 4; i++)
#pragma unroll
        for (int j = 0; j < 4; j++) acc[i][j] = (f32x4){0.f, 0.f, 0.f, 0.f};

    const int srow = tid >> 2;
    const int soff = (tid & 3) << 3;
    int arow1 = tileM + srow;       if (arow1 > MROWS - 1) arow1 = MROWS - 1;
    int arow2 = tileM + srow + 64;  if (arow2 > MROWS - 1) arow2 = MROWS - 1;
    const unsigned short* Aptr  = A + (size_t)arow1 * K + soff;
    const unsigned short* Aptr2 = A + (size_t)arow2 * K + soff;
    const unsigned short* Wp    = W + (size_t)(tileN + srow) * Wstride + soff;
    const unsigned short* Wp2   = Wp + (size_t)64 * Wstride;

    auto STAGE = [&](int buf, int k0) {
        gl2lds(Aptr  + k0, &Alds[buf][wave * 512]);
        gl2lds(Aptr2 + k0, &Alds[buf][2048 + wave * 512]);
        gl2lds(Wp    + k0, &Blds[buf][wave * 512]);
        gl2lds(Wp2   + k0, &Blds[buf][2048 + wave * 512]);
    };

    auto COMPUTE = [&](int buf) {
        bf16x8 af[4], bfr[4];
#pragma unroll
        for (int mi = 0; mi < 4; mi++) af[mi]  = ld_bf8(&Alds[buf][(wm + mi * 16 + l16) * 32 + q * 8]);
#pragma unroll
        for (int ni = 0; ni < 4; ni++) bfr[ni] = ld_bf8(&Blds[buf][(wn + ni * 16 + l16) * 32 + q * 8]);
#pragma unroll
        for (int mi = 0; mi < 4; mi++)
#pragma unroll
            for (int ni = 0; ni < 4; ni++)
                acc[mi][ni] = __builtin_amdgcn_mfma_f32_16x16x32_bf16(af[mi], bfr[ni], acc[mi][ni], 0, 0, 0);
    };

    const int NT = K >> 5;
    STAGE(0, 0);
    __syncthreads();           // vmcnt(0) drain: buf0 populated
    int cur = 0;
    for (int t = 0; t < NT; ++t) {
        if (t + 1 < NT) STAGE(cur ^ 1, (t + 1) << 5);
        COMPUTE(cur);
        __syncthreads();       // prefetch landed + all reads of cur done
        cur ^= 1;
    }

#pragma unroll
    for (int mi = 0; mi < 4; mi++) {
#pragma unroll
        for (int r = 0; r < 4; r++) {
            int row = tileM + wm + mi * 16 + q * 4 + r;
            if (row >= MROWS) continue;
#pragma unroll
            for (int ni = 0; ni < 4; ni++) {
                int col = tileN + wn + ni * 16 + l16;
                size_t oidx = (size_t)row * Nout + col;
                float v = acc[mi][ni][r];
                if constexpr (OP != 4) v += bf2f(bias[col]);
                if constexpr (OP == 1) {
                    v += ((const float*)Res)[oidx];
                    ((unsigned short*)Out)[oidx] = f2bf(v);
                } else if constexpr (OP == 3) {
                    v += bf2f(((const unsigned short*)Res)[oidx]);
                    ((float*)Out)[oidx] = v;
                } else {
                    ((float*)Out)[oidx] += v;
                }
            }
        }
    }
}

// ============ GEMM B: 256x256 tile, BK=64, 8 waves, 2-phase prefetch ========
// 1 block/CU (128 KiB LDS). For large-N GEMMs (qkv 876 blocks, fc1 1168).
// XCD-chunked 1D grid.
// OP=0: +bias, qkv split-scatter (Out=Qb *QSCALE, Out2=Kb, Out3=Vt transposed)
// OP=2: +bias, GELU, bf16 out (fc1)
template<int OP>
__global__ __launch_bounds__(512, 2) void gemm256(
    const unsigned short* __restrict__ A,
    const unsigned short* __restrict__ W, int Wstride,
    const unsigned short* __restrict__ bias,
    void* __restrict__ Out,
    void* __restrict__ Out2,
    void* __restrict__ Out3,
    int K, int Nout, int ntn)
{
    __shared__ __align__(16) unsigned short Alds[2][256 * 64];
    __shared__ __align__(16) unsigned short Blds[2][256 * 64];

    const int tid  = threadIdx.x;
    const int lane = tid & 63, wave = tid >> 6;
    const int q = lane >> 4, l16 = lane & 15;
    const int wm = (wave >> 2) << 7;   // 0 or 128 (M half)
    const int wn = (wave & 3) << 6;    // 0/64/128/192 (N quarter)

    const int logical = xcd_chunk_logical(blockIdx.x, gridDim.x);
    const int tileM = (logical / ntn) << 8;
    const int tileN = (logical % ntn) << 8;

    f32x4 acc[8][4];
#pragma unroll
    for (int i = 0; i < 8; i++)
#pragma unroll
        for (int j = 0; j < 4; j++) acc[i][j] = (f32x4){0.f, 0.f, 0.f, 0.f};

    const int srow = tid >> 3;          // 0..63
    const int scol = (tid & 7) << 3;    // 0..56
    const unsigned short* pA[4];
    const unsigned short* pB[4];
#pragma unroll
    for (int j = 0; j < 4; j++) {
        int ra = tileM + j * 64 + srow; if (ra > MROWS - 1) ra = MROWS - 1;
        pA[j] = A + (size_t)ra * K + scol;
        pB[j] = W + (size_t)(tileN + j * 64 + srow) * Wstride + scol;
    }

    auto STAGE = [&](int buf, int k0) {
#pragma unroll
        for (int j = 0; j < 4; j++) {
            gl2lds(pA[j] + k0, &Alds[buf][j * 4096 + wave * 512]);
            gl2lds(pB[j] + k0, &Blds[buf][j * 4096 + wave * 512]);
        }
    };

    auto COMPUTE = [&](int buf) {
#pragma unroll
        for (int ks = 0; ks < 2; ks++) {
            bf16x8 af[8], bfr[4];
#pragma unroll
            for (int mi = 0; mi < 8; mi++)
                af[mi] = ld_bf8(&Alds[buf][(wm + mi * 16 + l16) * 64 + ks * 32 + q * 8]);
#pragma unroll
            for (int ni = 0; ni < 4; ni++)
                bfr[ni] = ld_bf8(&Blds[buf][(wn + ni * 16 + l16) * 64 + ks * 32 + q * 8]);
#pragma unroll
            for (int mi = 0; mi < 8; mi++)
#pragma unroll
                for (int ni = 0; ni < 4; ni++)
                    acc[mi][ni] = __builtin_amdgcn_mfma_f32_16x16x32_bf16(af[mi], bfr[ni], acc[mi][ni], 0, 0, 0);
        }
    };

    const int NT = K >> 6;
    STAGE(0, 0);
    __syncthreads();
    int cur = 0;
    for (int t = 0; t < NT; ++t) {
        if (t + 1 < NT) STAGE(cur ^ 1, (t + 1) << 6);
        COMPUTE(cur);
        __syncthreads();
        cur ^= 1;
    }

#pragma unroll
    for (int mi = 0; mi < 8; mi++) {
#pragma unroll
        for (int r = 0; r < 4; r++) {
            int row = tileM + wm + mi * 16 + q * 4 + r;
            if (row >= MROWS) continue;
            unsigned int bb = 0, nn = 0;
            if constexpr (OP == 0) {
                bb = ((unsigned int)row * 58154u) >> 25;   // row/577, exact for row<78766
                nn = (unsigned int)row - bb * 577u;
            }
#pragma unroll
            for (int ni = 0; ni < 4; ni++) {
                int col = tileN + wn + ni * 16 + l16;
                size_t oidx = (size_t)row * Nout + col;
                float v = acc[mi][ni][r] + bf2f(bias[col]);
                if constexpr (OP == 0) {
                    int s = col >> 10, h = (col >> 6) & 15, d = col & 63;
                    size_t bh = (size_t)(bb * 16 + h);
                    if (s == 0)      ((unsigned short*)Out )[(bh * NTOK + nn) * 64 + d] = f2bf(v * QSCALE);
                    else if (s == 1) ((unsigned short*)Out2)[(bh * NTOK + nn) * 64 + d] = f2bf(v);
                    else             ((unsigned short*)Out3)[(bh * 64 + d) * NPADV + nn] = f2bf(v);
                } else {  // OP == 2
                    ((unsigned short*)Out)[oidx] = f2bf(gelu_f(v));
                }
            }
        }
    }
}

// ---------------- Flash attention, no-max unnormalized softmax ----------------
__global__ __launch_bounds__(256) void attn_kernel(
    const unsigned short* __restrict__ Qb,
    const unsigned short* __restrict__ Kb,
    const unsigned short* __restrict__ Vt,
    unsigned short* __restrict__ o)
{
    const int flat = blockIdx.x;
    const int x8 = flat & 7;
    const int g = flat >> 3;
    const int qt = g % 10;
    const int bh = (g / 10) * 8 + x8;      // b*16 + h
    const int q0 = qt * 64;
    const int tid = threadIdx.x;
    const int wv = tid >> 6, lane = tid & 63;
    const int qd = lane >> 4, l16 = lane & 15;

    __shared__ __align__(16) unsigned short Ps[4][16 * 72];

    const unsigned short* Qh = Qb + (size_t)bh * NTOK * 64;
    const unsigned short* Kh = Kb + (size_t)bh * NTOK * 64;
    const unsigned short* Vh = Vt + (size_t)bh * 64 * NPADV;

    int qrow = q0 + wv * 16 + l16;
    int qr = qrow < NTOK ? qrow : NTOK - 1;
    bf16x8 qf0 = ld_bf8(Qh + (size_t)qr * 64 + qd * 8);
    bf16x8 qf1 = ld_bf8(Qh + (size_t)qr * 64 + 32 + qd * 8);

    float lsum[4];
    f32x4 Oacc[4];
#pragma unroll
    for (int r = 0; r < 4; r++) lsum[r] = 0.f;
#pragma unroll
    for (int ni = 0; ni < 4; ni++) Oacc[ni] = (f32x4){0.f, 0.f, 0.f, 0.f};

    for (int kt = 0; kt < 10; kt++) {
        const int k0 = kt * 64;
        const bool tail = (kt == 9);
        f32x4 sacc[4];
#pragma unroll
        for (int ni = 0; ni < 4; ni++) sacc[ni] = (f32x4){0.f, 0.f, 0.f, 0.f};
#pragma unroll
        for (int ni = 0; ni < 4; ni++) {
            int krow = k0 + ni * 16 + l16;
            if (krow > NTOK - 1) krow = NTOK - 1;
            const unsigned short* kp = Kh + (size_t)krow * 64 + qd * 8;
            bf16x8 b0 = ld_bf8(kp);
            bf16x8 b1 = ld_bf8(kp + 32);
            sacc[ni] = __builtin_amdgcn_mfma_f32_16x16x32_bf16(qf0, b0, sacc[ni], 0, 0, 0);
            sacc[ni] = __builtin_amdgcn_mfma_f32_16x16x32_bf16(qf1, b1, sacc[ni], 0, 0, 0);
        }

#pragma unroll
        for (int r = 0; r < 4; r++) {
#pragma unroll
            for (int ni = 0; ni < 4; ni++) {
                float pv = exp2f(sacc[ni][r]);
                if (tail && (k0 + ni * 16 + l16 >= NTOK)) pv = 0.f;
                lsum[r] += pv;
                Ps[wv][(qd * 4 + r) * 72 + ni * 16 + l16] = f2bf(pv);
            }
        }

#pragma unroll
        for (int kk = 0; kk < 2; kk++) {
            bf16x8 a = ld_bf8(&Ps[wv][l16 * 72 + kk * 32 + qd * 8]);
            int kchunk = k0 + kk * 32 + qd * 8;
            if (kchunk > NTOK - 1) kchunk = NTOK - 1;  // clamped chunks have P==0
#pragma unroll
            for (int ni = 0; ni < 4; ni++) {
                bf16x8 bb = ld_bf8(Vh + (size_t)(ni * 16 + l16) * NPADV + kchunk);
                Oacc[ni] = __builtin_amdgcn_mfma_f32_16x16x32_bf16(a, bb, Oacc[ni], 0, 0, 0);
            }
        }
    }

#pragma unroll
    for (int r = 0; r < 4; r++)
#pragma unroll
        for (int off = 8; off > 0; off >>= 1) lsum[r] += __shfl_xor(lsum[r], off);

    const int b = bh >> 4, h = bh & 15;
#pragma unroll
    for (int r = 0; r < 4; r++) {
        int gq = q0 + wv * 16 + qd * 4 + r;
        if (gq >= NTOK) continue;
        float inv = 1.0f / lsum[r];
#pragma unroll
        for (int ni = 0; ni < 4; ni++) {
            int d = ni * 16 + l16;
            o[((size_t)b * NTOK + gq) * CDIM + (size_t)h * 64 + d] = f2bf(Oacc[ni][r] * inv);
        }
    }
}

// ---------------- launch ----------------
extern "C" void kernel_launch(void* const* d_in, const int* in_sizes, int n_in,
                              void* d_out, int out_size, void* d_ws, size_t ws_size,
                              hipStream_t stream) {
    (void)in_sizes; (void)n_in; (void)out_size;
    const float* x      = (const float*)d_in[0];
    const float* ln1_w  = (const float*)d_in[1];
    const float* ln1_b  = (const float*)d_in[2];
    const float* qkv_w  = (const float*)d_in[3];
    const float* qkv_b  = (const float*)d_in[4];
    const float* proj_w = (const float*)d_in[5];
    const float* proj_b = (const float*)d_in[6];
    const float* ln2_w  = (const float*)d_in[7];
    const float* ln2_b  = (const float*)d_in[8];
    const float* fc1_w  = (const float*)d_in[9];
    const float* fc1_b  = (const float*)d_in[10];
    const float* fc2_w  = (const float*)d_in[11];
    const float* fc2_b  = (const float*)d_in[12];

    // ---- ws layout: converted weights, then big regions ----
    char* ws = (char*)d_ws;
    size_t off = 0;
    auto alloc = [&](size_t els) { void* p = ws + off; off += els * 2; return (unsigned short*)p; };
    unsigned short* qkvw_b  = alloc(3145728);
    unsigned short* projw_b = alloc(1048576);
    unsigned short* fc1w_b  = alloc(4194304);
    unsigned short* fc2w_b  = alloc(4194304);
    unsigned short* qkvb_b  = alloc(3072);
    unsigned short* projb_b = alloc(1024);
    unsigned short* fc1b_b  = alloc(4096);
    unsigned short* fc2b_b  = alloc(1024);
    off = (off + 255) & ~(size_t)255;
    unsigned short* R1 = (unsigned short*)(ws + off); off += (size_t)MROWS * 1024 * 2;          // Kb -> x1
    unsigned short* R2 = (unsigned short*)(ws + off); off += (size_t)512 * 64 * NPADV * 2;      // Vt -> h2
    unsigned short* R3 = (unsigned short*)(ws + off);                                           // fc1 out
    size_t rem = ws_size > off ? ws_size - off : 0;
    const int CH = rem >= (size_t)MROWS * H4DIM * 2 ? H4DIM
                 : (rem >= (size_t)MROWS * 1024 * 2 ? 1024
                 : (rem >= (size_t)MROWS * 512 * 2 ? 512 : 256));

    // d_out (f32 [M,1024] = 75.6MB) used as scratch: half1 = Qb, half2 = h1 then obuf
    unsigned short* Qb   = (unsigned short*)d_out;
    unsigned short* h1   = Qb + (size_t)MROWS * 1024;
    unsigned short* obuf = h1;
    unsigned short* Kb = R1;
    unsigned short* Vt = R2;
    unsigned short* x1 = R1;
    unsigned short* h2 = R2;

    // weight/bias conversion (every call; graph-safe)
    conv_kernel<<<3145728 / 1024, 256, 0, stream>>>(qkv_w,  qkvw_b,  3145728);
    conv_kernel<<<1048576 / 1024, 256, 0, stream>>>(proj_w, projw_b, 1048576);
    conv_kernel<<<4194304 / 1024, 256, 0, stream>>>(fc1_w,  fc1w_b,  4194304);
    conv_kernel<<<4194304 / 1024, 256, 0, stream>>>(fc2_w,  fc2w_b,  4194304);
    conv_kernel<<<3, 256, 0, stream>>>(qkv_b,  qkvb_b,  3072);
    conv_kernel<<<1, 256, 0, stream>>>(proj_b, projb_b, 1024);
    conv_kernel<<<4, 256, 0, stream>>>(fc1_b,  fc1b_b,  4096);
    conv_kernel<<<1, 256, 0, stream>>>(fc2_b,  fc2b_b,  1024);

    const int mt128 = (MROWS + 127) / 128;  // 145
    const int mt256 = (MROWS + 255) / 256;  // 73

    // h1 = LN1(x)
    ln_kernel<true><<<MROWS, 256, 0, stream>>>(x, ln1_w, ln1_b, h1);
    // qkv GEMM -> split Qb/Kb/Vt  (N=3072: 876 blocks; 12 N-tiles/row on 1 XCD)
    gemm256<0><<<(C3DIM / 256) * mt256, 512, 0, stream>>>(
        h1, qkvw_b, CDIM, qkvb_b, Qb, Kb, Vt, CDIM, C3DIM, C3DIM / 256);
    // attention -> obuf (overwrites h1; h1 dead)
    attn_kernel<<<5120, 256, 0, stream>>>(Qb, Kb, Vt, obuf);
    // x1 = bf16(x + obuf @ proj_w^T + proj_b)
    gemm128<1><<<(CDIM / 128) * mt128, 256, 0, stream>>>(
        obuf, projw_b, CDIM, projb_b, x, x1, CDIM, CDIM, CDIM / 128);
    // h2 = LN2(x1)   (Vt dead)
    ln_kernel<false><<<MROWS, 256, 0, stream>>>(x1, ln2_w, ln2_b, h2);

    if (CH == H4DIM) {
        // fc1 (N=4096: 1168 blocks; 16 N-tiles/row on 1 XCD)
        gemm256<2><<<(H4DIM / 256) * mt256, 512, 0, stream>>>(
            h2, fc1w_b, CDIM, fc1b_b, R3, nullptr, nullptr, CDIM, H4DIM, H4DIM / 256);
        // fc2 (A = 151 MB R3; XCD-chunked + prefetch pipeline)
        gemm128<3><<<(CDIM / 128) * mt128, 256, 0, stream>>>(
            R3, fc2w_b, H4DIM, fc2b_b, x1, d_out, H4DIM, CDIM, CDIM / 128);
    } else {
        for (int c0 = 0; c0 < H4DIM; c0 += CH) {
            gemm256<2><<<(CH / 256) * mt256, 512, 0, stream>>>(
                h2, fc1w_b + (size_t)c0 * CDIM, CDIM, fc1b_b + c0, R3, nullptr, nullptr, CDIM, CH, CH / 256);
            if (c0 == 0)
                gemm128<3><<<(CDIM / 128) * mt128, 256, 0, stream>>>(
                    R3, fc2w_b, H4DIM, fc2b_b, x1, d_out, CH, CDIM, CDIM / 128);
            else
                gemm128<4><<<(CDIM / 128) * mt128, 256, 0, stream>>>(
                    R3, fc2w_b + c0, H4DIM, nullptr, nullptr, d_out, CH, CDIM, CDIM / 128);
        }
    }
}

// Round 5
// 1118.979 us; speedup vs baseline: 1.1557x; 1.0338x over previous
//
#include <hip/hip_runtime.h>
#include <math.h>

// ---- problem constants ----
#define BATCH  32
#define NTOK   577
#define CDIM   1024
#define C3DIM  3072
#define H4DIM  4096
#define NHEAD  16
#define MROWS  (BATCH * NTOK)   // 18464
#define NPADV  584              // 577 rounded up to 8 (V^T row pad)

typedef __bf16 bf16x8 __attribute__((ext_vector_type(8)));
typedef float  f32x4  __attribute__((ext_vector_type(4)));
typedef unsigned short u16x8 __attribute__((ext_vector_type(8)));

__device__ __forceinline__ float bf2f(unsigned short u) {
    union { unsigned int i; float f; } v; v.i = ((unsigned int)u) << 16; return v.f;
}
__device__ __forceinline__ unsigned short f2bf(float f) {
    union { float f; unsigned int i; } v; v.f = f;
    unsigned int r = v.i + 0x7FFFu + ((v.i >> 16) & 1u);
    return (unsigned short)(r >> 16);
}
__device__ __forceinline__ bf16x8 ld_bf8(const unsigned short* p) {
    return __builtin_bit_cast(bf16x8, *(const u16x8*)p);
}

// async global->LDS, 16B per lane. LDS dest = wave-uniform base + lane*16.
typedef const __attribute__((address_space(1))) unsigned int* gptr_t;
typedef __attribute__((address_space(3))) unsigned int* lptr_t;
__device__ __forceinline__ void gl2lds(const void* g, const void* l) {
    __builtin_amdgcn_global_load_lds(
        (gptr_t)(unsigned long long)g,
        (lptr_t)(unsigned int)(unsigned long long)l,
        16, 0, 0);
}

// Bijective chunked XCD remap (m204): blocks round-robin across 8 XCDs by
// hardware flat index; give each XCD a CONTIGUOUS chunk of the logical tile
// order. (r3 verified: fc2 FETCH 674 MB -> 167 MB.)
__device__ __forceinline__ int xcd_chunk_logical(int orig, int nwg) {
    int xcd = orig & 7, k = orig >> 3;
    int q = nwg >> 3, r = nwg & 7;
    int base = xcd < r ? xcd * (q + 1) : r * (q + 1) + (xcd - r) * q;
    return base + k;
}

// Q pre-scale: Dh^-0.5 * log2(e), so softmax runs in exp2 domain
#define QSCALE 0.18033688011112042f

// GELU tanh-form in exp2 domain: max |err| vs erf-GELU ~3e-4 << bf16 noise.
__device__ __forceinline__ float gelu_f(float v) {
    float z = exp2f(v * fmaf(v * v, 0.1029432f, 2.3022082f));
    return v - v * __builtin_amdgcn_rcpf(1.0f + z);
}

// ---------------- f32 -> bf16 convert ----------------
__global__ __launch_bounds__(256) void conv_kernel(const float* __restrict__ src,
                                                   unsigned short* __restrict__ dst, int n) {
    int i = (blockIdx.x * 256 + threadIdx.x) * 4;
    if (i < n) {
        float4 v = *(const float4*)(src + i);
        dst[i]     = f2bf(v.x);
        dst[i + 1] = f2bf(v.y);
        dst[i + 2] = f2bf(v.z);
        dst[i + 3] = f2bf(v.w);
    }
}

// ---------------- LayerNorm ----------------
template<bool F32IN>
__global__ __launch_bounds__(256) void ln_kernel(
    const void* __restrict__ X,
    const float* __restrict__ w,
    const float* __restrict__ b,
    unsigned short* __restrict__ out)
{
    const int row = blockIdx.x;
    const int t = threadIdx.x;
    float vals[4]; float s = 0.f, ss = 0.f;
#pragma unroll
    for (int i = 0; i < 4; i++) {
        int c = t + i * 256;
        float v;
        if (F32IN) v = ((const float*)X)[(size_t)row * CDIM + c];
        else       v = bf2f(((const unsigned short*)X)[(size_t)row * CDIM + c]);
        vals[i] = v; s += v; ss += v * v;
    }
#pragma unroll
    for (int off = 32; off > 0; off >>= 1) { s += __shfl_xor(s, off); ss += __shfl_xor(ss, off); }
    __shared__ float red[8];
    if ((t & 63) == 0) { red[t >> 6] = s; red[4 + (t >> 6)] = ss; }
    __syncthreads();
    s  = red[0] + red[1] + red[2] + red[3];
    ss = red[4] + red[5] + red[6] + red[7];
    float mu  = s * (1.f / CDIM);
    float var = ss * (1.f / CDIM) - mu * mu;
    float rs  = rsqrtf(var + 1e-6f);
#pragma unroll
    for (int i = 0; i < 4; i++) {
        int c = t + i * 256;
        float o = (vals[i] - mu) * rs * w[c] + b[c];
        out[(size_t)row * CDIM + c] = f2bf(o);
    }
}

// ============ GEMM A: 128x128 tile, BK=32, 4 waves, depth-2 pipeline ========
// 3 LDS buffers (48 KiB, 3 blocks/CU). Counted vmcnt: tile t's 4 loads/wave
// were issued 2 iterations back; vmcnt(4) allows t+1's to stay in flight
// (T4/m218: counted-vs-drain0 is +38-73%). One raw s_barrier per K-step.
// OP=1: +bias, + f32 residual (Res=x), bf16 out (x1)
// OP=3: +bias, + bf16 residual (x1), f32 out to d_out
// OP=4: f32 accumulate into d_out (no bias)
template<int OP>
__global__ __launch_bounds__(256) void gemm128(
    const unsigned short* __restrict__ A,
    const unsigned short* __restrict__ W, int Wstride,
    const unsigned short* __restrict__ bias,
    const void* __restrict__ Res,
    void* __restrict__ Out,
    int K, int Nout, int ntn)
{
    __shared__ __align__(16) unsigned short Alds[3][128 * 32];
    __shared__ __align__(16) unsigned short Blds[3][128 * 32];
    const int tid  = threadIdx.x;
    const int lane = tid & 63, wave = tid >> 6;
    const int q = lane >> 4, l16 = lane & 15;
    const int wm = (wave & 1) << 6, wn = (wave >> 1) << 6;

    const int logical = xcd_chunk_logical(blockIdx.x, gridDim.x);
    const int tileM = (logical / ntn) << 7;
    const int tileN = (logical % ntn) << 7;

    f32x4 acc[4][4];
#pragma unroll
    for (int i = 0; i < 4; i++)
#pragma unroll
        for (int j = 0; j < 4; j++) acc[i][j] = (f32x4){0.f, 0.f, 0.f, 0.f};

    const int srow = tid >> 2;          // 0..63
    const int soff = (tid & 3) << 3;
    const unsigned short* pA[2];
    const unsigned short* pB[2];
#pragma unroll
    for (int j = 0; j < 2; j++) {
        int ra = tileM + j * 64 + srow; if (ra > MROWS - 1) ra = MROWS - 1;
        pA[j] = A + (size_t)ra * K + soff;
        pB[j] = W + (size_t)(tileN + j * 64 + srow) * Wstride + soff;
    }

    auto STAGE = [&](int buf, int k0) {   // 4 gl2lds per wave
#pragma unroll
        for (int j = 0; j < 2; j++) {
            gl2lds(pA[j] + k0, &Alds[buf][j * 2048 + wave * 512]);
            gl2lds(pB[j] + k0, &Blds[buf][j * 2048 + wave * 512]);
        }
    };

    auto COMPUTE = [&](int buf) {
        bf16x8 af[4], bfr[4];
#pragma unroll
        for (int mi = 0; mi < 4; mi++) af[mi]  = ld_bf8(&Alds[buf][(wm + mi * 16 + l16) * 32 + q * 8]);
#pragma unroll
        for (int ni = 0; ni < 4; ni++) bfr[ni] = ld_bf8(&Blds[buf][(wn + ni * 16 + l16) * 32 + q * 8]);
#pragma unroll
        for (int mi = 0; mi < 4; mi++)
#pragma unroll
            for (int ni = 0; ni < 4; ni++)
                acc[mi][ni] = __builtin_amdgcn_mfma_f32_16x16x32_bf16(af[mi], bfr[ni], acc[mi][ni], 0, 0, 0);
    };

    const int NT = K >> 5;               // >= 32 for all our K
    STAGE(0, 0);
    STAGE(1, 32);
    int t = 0;
    for (; t < NT - 1; ++t) {
        asm volatile("s_waitcnt vmcnt(4)" ::: "memory");   // t's landed; t+1 in flight
        __builtin_amdgcn_s_barrier();
        __builtin_amdgcn_sched_barrier(0);
        if (t + 2 < NT) STAGE((t + 2) % 3, (t + 2) << 5);
        COMPUTE(t % 3);
    }
    asm volatile("s_waitcnt vmcnt(0)" ::: "memory");
    __builtin_amdgcn_s_barrier();
    __builtin_amdgcn_sched_barrier(0);
    COMPUTE(t % 3);

#pragma unroll
    for (int mi = 0; mi < 4; mi++) {
#pragma unroll
        for (int r = 0; r < 4; r++) {
            int row = tileM + wm + mi * 16 + q * 4 + r;
            if (row >= MROWS) continue;
#pragma unroll
            for (int ni = 0; ni < 4; ni++) {
                int col = tileN + wn + ni * 16 + l16;
                size_t oidx = (size_t)row * Nout + col;
                float v = acc[mi][ni][r];
                if constexpr (OP != 4) v += bf2f(bias[col]);
                if constexpr (OP == 1) {
                    v += ((const float*)Res)[oidx];
                    ((unsigned short*)Out)[oidx] = f2bf(v);
                } else if constexpr (OP == 3) {
                    v += bf2f(((const unsigned short*)Res)[oidx]);
                    ((float*)Out)[oidx] = v;
                } else {
                    ((float*)Out)[oidx] += v;
                }
            }
        }
    }
}

// ============ GEMM B: 256x256 tile, BK=32, 8 waves, depth-2 pipeline ========
// 3 LDS buffers (96 KiB, 1 block/CU), counted vmcnt(4) + raw s_barrier.
// M-banded logical order (bands of 4 M-panels, m fastest): W-tile reused 4x
// from L2 within a band -> W L3/HBM re-read cut ~4x (r4: FETCH 168 MB vs 46 min).
// OP=0: +bias, qkv split-scatter (Out=Qb *QSCALE, Out2=Kb, Out3=Vt transposed)
// OP=2: +bias, GELU, bf16 out (fc1)
template<int OP>
__global__ __launch_bounds__(512, 2) void gemm256(
    const unsigned short* __restrict__ A,
    const unsigned short* __restrict__ W, int Wstride,
    const unsigned short* __restrict__ bias,
    void* __restrict__ Out,
    void* __restrict__ Out2,
    void* __restrict__ Out3,
    int K, int Nout, int ntn)
{
    __shared__ __align__(16) unsigned short Alds[3][256 * 32];
    __shared__ __align__(16) unsigned short Blds[3][256 * 32];

    const int tid  = threadIdx.x;
    const int lane = tid & 63, wave = tid >> 6;
    const int q = lane >> 4, l16 = lane & 15;
    const int wm = (wave >> 2) << 7;   // 0 or 128 (M half)
    const int wn = (wave & 3) << 6;    // 0/64/128/192 (N quarter)

    // banded decode: band of 4 M-panels, m fastest within band (bijective incl. tail)
    const int logical = xcd_chunk_logical(blockIdx.x, gridDim.x);
    const int ntm = gridDim.x / ntn;
    const int per_band = ntn << 2;
    const int band = logical / per_band;
    const int rb = logical % per_band;
    const int mb0 = band << 2;
    const int rows = (ntm - mb0) < 4 ? (ntm - mb0) : 4;
    const int tileN = (rb / rows) << 8;
    const int tileM = (mb0 + rb % rows) << 8;

    f32x4 acc[8][4];
#pragma unroll
    for (int i = 0; i < 8; i++)
#pragma unroll
        for (int j = 0; j < 4; j++) acc[i][j] = (f32x4){0.f, 0.f, 0.f, 0.f};

    const int srow = tid >> 2;          // 0..127
    const int scol = (tid & 3) << 3;    // 0..24
    const unsigned short* pA[2];
    const unsigned short* pB[2];
#pragma unroll
    for (int j = 0; j < 2; j++) {
        int ra = tileM + j * 128 + srow; if (ra > MROWS - 1) ra = MROWS - 1;
        pA[j] = A + (size_t)ra * K + scol;
        pB[j] = W + (size_t)(tileN + j * 128 + srow) * Wstride + scol;
    }

    auto STAGE = [&](int buf, int k0) {   // 4 gl2lds per wave
#pragma unroll
        for (int j = 0; j < 2; j++) {
            gl2lds(pA[j] + k0, &Alds[buf][j * 4096 + wave * 512]);
            gl2lds(pB[j] + k0, &Blds[buf][j * 4096 + wave * 512]);
        }
    };

    auto COMPUTE = [&](int buf) {
        bf16x8 af[8], bfr[4];
#pragma unroll
        for (int mi = 0; mi < 8; mi++)
            af[mi] = ld_bf8(&Alds[buf][(wm + mi * 16 + l16) * 32 + q * 8]);
#pragma unroll
        for (int ni = 0; ni < 4; ni++)
            bfr[ni] = ld_bf8(&Blds[buf][(wn + ni * 16 + l16) * 32 + q * 8]);
#pragma unroll
        for (int mi = 0; mi < 8; mi++)
#pragma unroll
            for (int ni = 0; ni < 4; ni++)
                acc[mi][ni] = __builtin_amdgcn_mfma_f32_16x16x32_bf16(af[mi], bfr[ni], acc[mi][ni], 0, 0, 0);
    };

    const int NT = K >> 5;
    STAGE(0, 0);
    STAGE(1, 32);
    int t = 0;
    for (; t < NT - 1; ++t) {
        asm volatile("s_waitcnt vmcnt(4)" ::: "memory");
        __builtin_amdgcn_s_barrier();
        __builtin_amdgcn_sched_barrier(0);
        if (t + 2 < NT) STAGE((t + 2) % 3, (t + 2) << 5);
        COMPUTE(t % 3);
    }
    asm volatile("s_waitcnt vmcnt(0)" ::: "memory");
    __builtin_amdgcn_s_barrier();
    __builtin_amdgcn_sched_barrier(0);
    COMPUTE(t % 3);

#pragma unroll
    for (int mi = 0; mi < 8; mi++) {
#pragma unroll
        for (int r = 0; r < 4; r++) {
            int row = tileM + wm + mi * 16 + q * 4 + r;
            if (row >= MROWS) continue;
            unsigned int bb = 0, nn = 0;
            if constexpr (OP == 0) {
                bb = ((unsigned int)row * 58154u) >> 25;   // row/577, exact for row<78766
                nn = (unsigned int)row - bb * 577u;
            }
#pragma unroll
            for (int ni = 0; ni < 4; ni++) {
                int col = tileN + wn + ni * 16 + l16;
                size_t oidx = (size_t)row * Nout + col;
                float v = acc[mi][ni][r] + bf2f(bias[col]);
                if constexpr (OP == 0) {
                    int s = col >> 10, h = (col >> 6) & 15, d = col & 63;
                    size_t bh = (size_t)(bb * 16 + h);
                    if (s == 0)      ((unsigned short*)Out )[(bh * NTOK + nn) * 64 + d] = f2bf(v * QSCALE);
                    else if (s == 1) ((unsigned short*)Out2)[(bh * NTOK + nn) * 64 + d] = f2bf(v);
                    else             ((unsigned short*)Out3)[(bh * 64 + d) * NPADV + nn] = f2bf(v);
                } else {  // OP == 2
                    ((unsigned short*)Out)[oidx] = f2bf(gelu_f(v));
                }
            }
        }
    }
}

// ---------------- Flash attention, no-max unnormalized softmax ----------------
__global__ __launch_bounds__(256) void attn_kernel(
    const unsigned short* __restrict__ Qb,
    const unsigned short* __restrict__ Kb,
    const unsigned short* __restrict__ Vt,
    unsigned short* __restrict__ o)
{
    const int flat = blockIdx.x;
    const int x8 = flat & 7;
    const int g = flat >> 3;
    const int qt = g % 10;
    const int bh = (g / 10) * 8 + x8;      // b*16 + h
    const int q0 = qt * 64;
    const int tid = threadIdx.x;
    const int wv = tid >> 6, lane = tid & 63;
    const int qd = lane >> 4, l16 = lane & 15;

    __shared__ __align__(16) unsigned short Ps[4][16 * 72];

    const unsigned short* Qh = Qb + (size_t)bh * NTOK * 64;
    const unsigned short* Kh = Kb + (size_t)bh * NTOK * 64;
    const unsigned short* Vh = Vt + (size_t)bh * 64 * NPADV;

    int qrow = q0 + wv * 16 + l16;
    int qr = qrow < NTOK ? qrow : NTOK - 1;
    bf16x8 qf0 = ld_bf8(Qh + (size_t)qr * 64 + qd * 8);
    bf16x8 qf1 = ld_bf8(Qh + (size_t)qr * 64 + 32 + qd * 8);

    float lsum[4];
    f32x4 Oacc[4];
#pragma unroll
    for (int r = 0; r < 4; r++) lsum[r] = 0.f;
#pragma unroll
    for (int ni = 0; ni < 4; ni++) Oacc[ni] = (f32x4){0.f, 0.f, 0.f, 0.f};

    for (int kt = 0; kt < 10; kt++) {
        const int k0 = kt * 64;
        const bool tail = (kt == 9);
        f32x4 sacc[4];
#pragma unroll
        for (int ni = 0; ni < 4; ni++) sacc[ni] = (f32x4){0.f, 0.f, 0.f, 0.f};
#pragma unroll
        for (int ni = 0; ni < 4; ni++) {
            int krow = k0 + ni * 16 + l16;
            if (krow > NTOK - 1) krow = NTOK - 1;
            const unsigned short* kp = Kh + (size_t)krow * 64 + qd * 8;
            bf16x8 b0 = ld_bf8(kp);
            bf16x8 b1 = ld_bf8(kp + 32);
            sacc[ni] = __builtin_amdgcn_mfma_f32_16x16x32_bf16(qf0, b0, sacc[ni], 0, 0, 0);
            sacc[ni] = __builtin_amdgcn_mfma_f32_16x16x32_bf16(qf1, b1, sacc[ni], 0, 0, 0);
        }

#pragma unroll
        for (int r = 0; r < 4; r++) {
#pragma unroll
            for (int ni = 0; ni < 4; ni++) {
                float pv = exp2f(sacc[ni][r]);
                if (tail && (k0 + ni * 16 + l16 >= NTOK)) pv = 0.f;
                lsum[r] += pv;
                Ps[wv][(qd * 4 + r) * 72 + ni * 16 + l16] = f2bf(pv);
            }
        }

#pragma unroll
        for (int kk = 0; kk < 2; kk++) {
            bf16x8 a = ld_bf8(&Ps[wv][l16 * 72 + kk * 32 + qd * 8]);
            int kchunk = k0 + kk * 32 + qd * 8;
            if (kchunk > NTOK - 1) kchunk = NTOK - 1;  // clamped chunks have P==0
#pragma unroll
            for (int ni = 0; ni < 4; ni++) {
                bf16x8 bb = ld_bf8(Vh + (size_t)(ni * 16 + l16) * NPADV + kchunk);
                Oacc[ni] = __builtin_amdgcn_mfma_f32_16x16x32_bf16(a, bb, Oacc[ni], 0, 0, 0);
            }
        }
    }

#pragma unroll
    for (int r = 0; r < 4; r++)
#pragma unroll
        for (int off = 8; off > 0; off >>= 1) lsum[r] += __shfl_xor(lsum[r], off);

    const int b = bh >> 4, h = bh & 15;
#pragma unroll
    for (int r = 0; r < 4; r++) {
        int gq = q0 + wv * 16 + qd * 4 + r;
        if (gq >= NTOK) continue;
        float inv = 1.0f / lsum[r];
#pragma unroll
        for (int ni = 0; ni < 4; ni++) {
            int d = ni * 16 + l16;
            o[((size_t)b * NTOK + gq) * CDIM + (size_t)h * 64 + d] = f2bf(Oacc[ni][r] * inv);
        }
    }
}

// ---------------- launch ----------------
extern "C" void kernel_launch(void* const* d_in, const int* in_sizes, int n_in,
                              void* d_out, int out_size, void* d_ws, size_t ws_size,
                              hipStream_t stream) {
    (void)in_sizes; (void)n_in; (void)out_size;
    const float* x      = (const float*)d_in[0];
    const float* ln1_w  = (const float*)d_in[1];
    const float* ln1_b  = (const float*)d_in[2];
    const float* qkv_w  = (const float*)d_in[3];
    const float* qkv_b  = (const float*)d_in[4];
    const float* proj_w = (const float*)d_in[5];
    const float* proj_b = (const float*)d_in[6];
    const float* ln2_w  = (const float*)d_in[7];
    const float* ln2_b  = (const float*)d_in[8];
    const float* fc1_w  = (const float*)d_in[9];
    const float* fc1_b  = (const float*)d_in[10];
    const float* fc2_w  = (const float*)d_in[11];
    const float* fc2_b  = (const float*)d_in[12];

    // ---- ws layout: converted weights, then big regions ----
    char* ws = (char*)d_ws;
    size_t off = 0;
    auto alloc = [&](size_t els) { void* p = ws + off; off += els * 2; return (unsigned short*)p; };
    unsigned short* qkvw_b  = alloc(3145728);
    unsigned short* projw_b = alloc(1048576);
    unsigned short* fc1w_b  = alloc(4194304);
    unsigned short* fc2w_b  = alloc(4194304);
    unsigned short* qkvb_b  = alloc(3072);
    unsigned short* projb_b = alloc(1024);
    unsigned short* fc1b_b  = alloc(4096);
    unsigned short* fc2b_b  = alloc(1024);
    off = (off + 255) & ~(size_t)255;
    unsigned short* R1 = (unsigned short*)(ws + off); off += (size_t)MROWS * 1024 * 2;          // Kb -> x1
    unsigned short* R2 = (unsigned short*)(ws + off); off += (size_t)512 * 64 * NPADV * 2;      // Vt -> h2
    unsigned short* R3 = (unsigned short*)(ws + off);                                           // fc1 out
    size_t rem = ws_size > off ? ws_size - off : 0;
    const int CH = rem >= (size_t)MROWS * H4DIM * 2 ? H4DIM
                 : (rem >= (size_t)MROWS * 1024 * 2 ? 1024
                 : (rem >= (size_t)MROWS * 512 * 2 ? 512 : 256));

    // d_out (f32 [M,1024] = 75.6MB) used as scratch: half1 = Qb, half2 = h1 then obuf
    unsigned short* Qb   = (unsigned short*)d_out;
    unsigned short* h1   = Qb + (size_t)MROWS * 1024;
    unsigned short* obuf = h1;
    unsigned short* Kb = R1;
    unsigned short* Vt = R2;
    unsigned short* x1 = R1;
    unsigned short* h2 = R2;

    // weight/bias conversion (every call; graph-safe)
    conv_kernel<<<3145728 / 1024, 256, 0, stream>>>(qkv_w,  qkvw_b,  3145728);
    conv_kernel<<<1048576 / 1024, 256, 0, stream>>>(proj_w, projw_b, 1048576);
    conv_kernel<<<4194304 / 1024, 256, 0, stream>>>(fc1_w,  fc1w_b,  4194304);
    conv_kernel<<<4194304 / 1024, 256, 0, stream>>>(fc2_w,  fc2w_b,  4194304);
    conv_kernel<<<3, 256, 0, stream>>>(qkv_b,  qkvb_b,  3072);
    conv_kernel<<<1, 256, 0, stream>>>(proj_b, projb_b, 1024);
    conv_kernel<<<4, 256, 0, stream>>>(fc1_b,  fc1b_b,  4096);
    conv_kernel<<<1, 256, 0, stream>>>(fc2_b,  fc2b_b,  1024);

    const int mt128 = (MROWS + 127) / 128;  // 145
    const int mt256 = (MROWS + 255) / 256;  // 73

    // h1 = LN1(x)
    ln_kernel<true><<<MROWS, 256, 0, stream>>>(x, ln1_w, ln1_b, h1);
    // qkv GEMM -> split Qb/Kb/Vt  (N=3072: 876 blocks)
    gemm256<0><<<(C3DIM / 256) * mt256, 512, 0, stream>>>(
        h1, qkvw_b, CDIM, qkvb_b, Qb, Kb, Vt, CDIM, C3DIM, C3DIM / 256);
    // attention -> obuf (overwrites h1; h1 dead)
    attn_kernel<<<5120, 256, 0, stream>>>(Qb, Kb, Vt, obuf);
    // x1 = bf16(x + obuf @ proj_w^T + proj_b)
    gemm128<1><<<(CDIM / 128) * mt128, 256, 0, stream>>>(
        obuf, projw_b, CDIM, projb_b, x, x1, CDIM, CDIM, CDIM / 128);
    // h2 = LN2(x1)   (Vt dead)
    ln_kernel<false><<<MROWS, 256, 0, stream>>>(x1, ln2_w, ln2_b, h2);

    if (CH == H4DIM) {
        // fc1 (N=4096: 1168 blocks)
        gemm256<2><<<(H4DIM / 256) * mt256, 512, 0, stream>>>(
            h2, fc1w_b, CDIM, fc1b_b, R3, nullptr, nullptr, CDIM, H4DIM, H4DIM / 256);
        // fc2 (A = 151 MB R3; XCD-chunked + depth-2 pipeline)
        gemm128<3><<<(CDIM / 128) * mt128, 256, 0, stream>>>(
            R3, fc2w_b, H4DIM, fc2b_b, x1, d_out, H4DIM, CDIM, CDIM / 128);
    } else {
        for (int c0 = 0; c0 < H4DIM; c0 += CH) {
            gemm256<2><<<(CH / 256) * mt256, 512, 0, stream>>>(
                h2, fc1w_b + (size_t)c0 * CDIM, CDIM, fc1b_b + c0, R3, nullptr, nullptr, CDIM, CH, CH / 256);
            if (c0 == 0)
                gemm128<3><<<(CDIM / 128) * mt128, 256, 0, stream>>>(
                    R3, fc2w_b, H4DIM, fc2b_b, x1, d_out, CH, CDIM, CDIM / 128);
            else
                gemm128<4><<<(CDIM / 128) * mt128, 256, 0, stream>>>(
                    R3, fc2w_b + c0, H4DIM, nullptr, nullptr, d_out, CH, CDIM, CDIM / 128);
        }
    }
}